// Round 3
// baseline (3546.906 us; speedup 1.0000x reference)
//
#include <hip/hip_runtime.h>

// ---------------------------------------------------------------------------
// EfficientDet head on MFMA (gfx950), split-bf16 (hi+lo) fp32-accurate GEMM.
// All convs = implicit GEMM: C[co][n] = W[co][k] * Im2col[k][n].
// Activations: NHWC bf16 hi/lo planes; 3x3 inputs spatially zero-padded P=S+2.
// K order for 3x3: k = (r*3+s)*256 + ci  (tap-major -> contiguous ci chunks).
// 3 MFMAs per tile-pair: AhiBhi + AhiBlo + AloBhi  (error ~2^-17 relative).
//
// R3: conv3p restructured around REGISTER-level fragment double-buffering:
//   chunk c's 48 MFMAs run entirely from regs (set X) while the LDS pipe
//   streams chunk c+1's 16 ds_reads (into set Y) and the DMA engine stages
//   chunk c+2 (global_load_lds). One s_barrier + one vmcnt(0) per chunk;
//   the vmcnt(0) drains a DMA issued at the TOP of the same chunk (~1500cyc
//   in-flight window >= HBM latency -> near-free). 3 rotating 48KB LDS bufs.
//   Safety: buffer staged in chunk c is read in c+1, rewritten in c+3 --
//   two barriers after its reads retire. Frag regs: 2 sets x 16 v8s = 128
//   VGPR + 64 acc, fits 2 waves/SIMD (<=256).
// 1x1 lateral + head-scatter convs keep the R1 128^2 global_load_lds kernel.
// ---------------------------------------------------------------------------

typedef unsigned short ush;
typedef __attribute__((ext_vector_type(8))) short v8s;
typedef __attribute__((ext_vector_type(4))) float v4f;

constexpr int TOTAL_ANCH = 196416;  // 9 * (128^2+64^2+32^2+16^2+8^2)

#define VMW(n) asm volatile("s_waitcnt vmcnt(" #n ")" ::: "memory")

__device__ __forceinline__ ush f2bf(float x) {
    unsigned u = __builtin_bit_cast(unsigned, x);
    u += 0x7FFFu + ((u >> 16) & 1u);
    return (ush)(u >> 16);
}
__device__ __forceinline__ float bf2f(ush h) {
    unsigned u = ((unsigned)h) << 16;
    return __builtin_bit_cast(float, u);
}
__device__ __forceinline__ void splitf(float x, ush& hi, ush& lo) {
    hi = f2bf(x);
    lo = f2bf(x - bf2f(hi));
}

__device__ __forceinline__ void gl_lds16(const ush* g, short* l) {
    __builtin_amdgcn_global_load_lds(
        (const __attribute__((address_space(1))) unsigned*)(const void*)g,
        (__attribute__((address_space(3))) unsigned*)l, 16, 0, 0);
}

// ---------------------------------------------------------------------------
// Deep-pipelined 3x3 conv: K=2304, Cout=256 (BM=256), BN=128 pixels/block.
// 8 waves: wm=w&3 (co quarter, 64 rows), wn=w>>2 (px half, 64 cols).
// LDS per buffer (48KB): Ah[256][32] | Al | Bh[128][32] | Bl  (shorts).
// Staging roles: waves 0-1 Ah, 2-3 Al, 4-5 Bh, 6-7 Bl; A-waves 8 DMA/chunk,
// B-waves 4.  Slot swizzle (both sides): seg(row,slot) = slot ^ ((row>>1)&3).
// OM: 0 = padded NHWC hi/lo out; 1 = unpadded NHWC hi/lo out.  BNR: BN+ReLU.
// ---------------------------------------------------------------------------
template <int OM, bool BNR>
__global__ __launch_bounds__(512, 2)
void conv3p(const ush* __restrict__ Xh, const ush* __restrict__ Xl,
            const ush* __restrict__ Wh, const ush* __restrict__ Wl,
            const float* __restrict__ bias,
            const float* __restrict__ bng, const float* __restrict__ bnb,
            const float* __restrict__ bnm, const float* __restrict__ bnv,
            ush* __restrict__ Yh, ush* __restrict__ Yl,
            int logS, int logHW)
{
    constexpr int K = 2304, KC = 72;
    constexpr int BUF = 24576;               // shorts per buffer
    const int S = 1 << logS, HW = 1 << logHW, P = S + 2;

    // bijective XCD-aware swizzle on the 1-D grid
    const int nwg = gridDim.x;
    const int flat = blockIdx.x;
    const int xcd = flat & 7, sidx = flat >> 3;
    const int q = nwg >> 3, r8 = nwg & 7;
    const int bx = (xcd < r8 ? xcd * (q + 1) : r8 * (q + 1) + (xcd - r8) * q) + sidx;
    const int n0 = bx * 128;

    __shared__ __align__(16) short lds[3][BUF];
    // per buffer offsets (shorts): Ah 0 | Al 8192 | Bh 16384 | Bl 20480

    const int tid = threadIdx.x;
    const int lane = tid & 63, w = tid >> 6;
    const int wm = w & 3, wn = w >> 2;
    const int l15 = lane & 15, l4 = lane >> 4;
    const int lr = lane >> 2, ls = lane & 3;
    const int sw = ls ^ ((lr >> 1) & 3);

    const int role = w >> 1, part = w & 1;   // role 0:Ah 1:Al 2:Bh 3:Bl
    const ush* gsrc = role == 0 ? Wh : role == 1 ? Wl : role == 2 ? Xh : Xl;
    const int poff = role < 2 ? role * 8192 : 16384 + (role - 2) * 4096;

    int sb[8];
    if (role < 2) {
#pragma unroll
        for (int t = 0; t < 8; ++t)
            sb[t] = (part * 128 + t * 16 + lr) * K + sw * 8;
    } else {
#pragma unroll
        for (int t = 0; t < 4; ++t) {
            const int p = n0 + part * 64 + t * 16 + lr;
            const int bb = p >> logHW, hw = p & (HW - 1);
            const int oh = hw >> logS, ow = hw & (S - 1);
            sb[t] = ((bb * P + oh + 1) * P + ow + 1) * 256 + sw * 8;
        }
    }

    // stage full chunk c into buffer at short-offset bo (A: 8 loads, B: 4)
    auto stage = [&](int bo, int c) {
        short* db = &lds[0][0] + bo + poff;
        if (role < 2) {
            const int coff = c * 32;
#pragma unroll
            for (int t = 0; t < 8; ++t)
                gl_lds16(gsrc + (sb[t] + coff), db + part * 4096 + t * 512);
        } else {
            const int rs = c >> 3;             // tap 0..8 (uniform)
            const int rr = (rs * 11) >> 5;     // rs / 3
            const int ss = rs - 3 * rr;
            const int coff = ((rr - 1) * P + (ss - 1)) * 256 + (c & 7) * 32;
#pragma unroll
            for (int t = 0; t < 4; ++t)
                gl_lds16(gsrc + (sb[t] + coff), db + part * 2048 + t * 512);
        }
    };

    // fragment read offsets (shorts)
    const int slr = (l4 ^ ((l15 >> 1) & 3)) * 8;
    int aoff[4], boff[4];
#pragma unroll
    for (int i = 0; i < 4; ++i) aoff[i] = (wm * 64 + i * 16 + l15) * 32 + slr;
#pragma unroll
    for (int j = 0; j < 4; ++j) boff[j] = (wn * 64 + j * 16 + l15) * 32 + slr;

    v4f acc[4][4] = {};
    v8s Xah[4], Xal[4], Xbh[4], Xbl[4];   // frag set X
    v8s Yah[4], Yal[4], Ybh[4], Ybl[4];   // frag set Y

    auto ldf = [&](int bo, v8s (&ah)[4], v8s (&al)[4],
                   v8s (&bh)[4], v8s (&bl)[4]) {
        const short* bb = &lds[0][0] + bo;
#pragma unroll
        for (int i = 0; i < 4; ++i) {
            ah[i] = *(const v8s*)(bb + aoff[i]);
            al[i] = *(const v8s*)(bb + 8192 + aoff[i]);
            bh[i] = *(const v8s*)(bb + 16384 + boff[i]);
            bl[i] = *(const v8s*)(bb + 20480 + boff[i]);
        }
    };
    auto compute = [&](v8s (&ah)[4], v8s (&al)[4],
                       v8s (&bh)[4], v8s (&bl)[4]) {
        __builtin_amdgcn_s_setprio(1);
#pragma unroll
        for (int j = 0; j < 4; ++j)
#pragma unroll
            for (int i = 0; i < 4; ++i) {
                acc[i][j] = __builtin_amdgcn_mfma_f32_16x16x32_bf16(ah[i], bh[j], acc[i][j], 0, 0, 0);
                acc[i][j] = __builtin_amdgcn_mfma_f32_16x16x32_bf16(ah[i], bl[j], acc[i][j], 0, 0, 0);
                acc[i][j] = __builtin_amdgcn_mfma_f32_16x16x32_bf16(al[i], bh[j], acc[i][j], 0, 0, 0);
            }
        __builtin_amdgcn_s_setprio(0);
    };

    // prologue: chunks 0,1 staged into buf0,buf1; preload chunk0 frags
    stage(0, 0); stage(BUF, 1);
    VMW(0);
    __builtin_amdgcn_sched_barrier(0);
    __builtin_amdgcn_s_barrier();
    ldf(0, Xah, Xal, Xbh, Xbl);

    // chunk c: data in buf[c%3]; reads of chunk c+1 from buf[(c+1)%3];
    // DMA for chunk c+2 into buf[(c+2)%3]. One barrier + one vmcnt(0)/chunk;
    // the drain covers a DMA issued at the top of the SAME chunk (hidden
    // under the 48-MFMA cluster + 16 ds_reads).
    int rdo = BUF, sto = 2 * BUF;
    for (int c = 0; c < KC; c += 2) {
        // ---- chunk c: compute X, load Y(chunk c+1), stage chunk c+2 ----
        if (c + 2 < KC) stage(sto, c + 2);
        ldf(rdo, Yah, Yal, Ybh, Ybl);          // c+1 <= KC-1 always (KC even)
        compute(Xah, Xal, Xbh, Xbl);
        VMW(0);
        __builtin_amdgcn_sched_barrier(0);
        __builtin_amdgcn_s_barrier();
        rdo += BUF; if (rdo == 3 * BUF) rdo = 0;
        sto += BUF; if (sto == 3 * BUF) sto = 0;

        // ---- chunk c+1: compute Y, load X(chunk c+2), stage chunk c+3 ----
        if (c + 3 < KC) stage(sto, c + 3);
        if (c + 2 < KC) ldf(rdo, Xah, Xal, Xbh, Xbl);
        compute(Yah, Yal, Ybh, Ybl);
        VMW(0);
        __builtin_amdgcn_sched_barrier(0);
        __builtin_amdgcn_s_barrier();
        rdo += BUF; if (rdo == 3 * BUF) rdo = 0;
        sto += BUF; if (sto == 3 * BUF) sto = 0;
    }

    // ---- epilogue: col = lane&15 (pixel), row = (lane>>4)*4+e (co) ----
#pragma unroll
    for (int i = 0; i < 4; ++i) {
        const int co = wm * 64 + i * 16 + l4 * 4;
        float sc[4], sh[4];
#pragma unroll
        for (int e = 0; e < 4; ++e) {
            if (BNR) {
                const float inv = bng[co + e] * rsqrtf(bnv[co + e] + 1e-5f);
                sc[e] = inv;
                sh[e] = (bias[co + e] - bnm[co + e]) * inv + bnb[co + e];
            } else { sc[e] = 1.f; sh[e] = bias[co + e]; }
        }
#pragma unroll
        for (int j = 0; j < 4; ++j) {
            const int ncol = n0 + wn * 64 + j * 16 + l15;
            const int b  = ncol >> logHW;
            const int hw = ncol & (HW - 1);
            float val[4];
#pragma unroll
            for (int e = 0; e < 4; ++e) {
                float x = acc[i][j][e] * sc[e] + sh[e];
                if (BNR) x = fmaxf(x, 0.f);
                val[e] = x;
            }
            int pidx;
            if (OM == 0) {
                const int oh = hw >> logS, ow = hw & (S - 1);
                pidx = (b * P + oh + 1) * P + ow + 1;
            } else {
                pidx = ncol;
            }
            const int addr = pidx * 256 + co;
            ush hs[4], ls2[4];
#pragma unroll
            for (int e = 0; e < 4; ++e) splitf(val[e], hs[e], ls2[e]);
            *(uint2*)&Yh[addr] = make_uint2(hs[0] | ((unsigned)hs[1] << 16),
                                            hs[2] | ((unsigned)hs[3] << 16));
            *(uint2*)&Yl[addr] = make_uint2(ls2[0] | ((unsigned)ls2[1] << 16),
                                            ls2[2] | ((unsigned)ls2[3] << 16));
        }
    }
}

// ---------------------------------------------------------------------------
// R1 128^2 kernel — retained for 1x1 lateral convs and head-scatter convs.
// KS: 1 (1x1, unpadded NHWC in, stride Kin)
// OM: 0 = padded NHWC hi/lo out; 2 = scatter fp32 out.  DD: out_dim (4/10).
// ---------------------------------------------------------------------------
template <int KS, int OM, bool BNR, int DD>
__global__ __launch_bounds__(256, 3)
void conv_mfma(const ush* __restrict__ Xh, const ush* __restrict__ Xl,
               const ush* __restrict__ Wh, const ush* __restrict__ Wl,
               const float* __restrict__ bias,
               const float* __restrict__ bng, const float* __restrict__ bnb,
               const float* __restrict__ bnm, const float* __restrict__ bnv,
               ush* __restrict__ Yh, ush* __restrict__ Yl,
               float* __restrict__ Yf,
               int K, int logS, int logHW, int Kin, int Cout,
               int abase, int coloff, int ibase)
{
    const int tid = threadIdx.x;

    const int nwg  = gridDim.x * gridDim.y;
    const int flat = blockIdx.y * gridDim.x + blockIdx.x;
    const int xcd = flat & 7, sidx = flat >> 3;
    const int q = nwg >> 3, r8 = nwg & 7;
    const int nf = (xcd < r8 ? xcd * (q + 1) : r8 * (q + 1) + (xcd - r8) * q) + sidx;
    int bx, by;
    if (gridDim.y == 2) { bx = nf >> 1; by = nf & 1; }
    else                { bx = nf;      by = 0;      }

    const int n0  = bx * 128;
    const int co0 = by * 128;
    const int S = 1 << logS, HW = 1 << logHW, P = S + 2;

    __shared__ short lds[4][128][32];

    const int lane = tid & 63;
    const int w = tid >> 6;
    const int wm = w & 1, wn = w >> 1;
    const int l15 = lane & 15, l4 = lane >> 4;

    const int lr = lane >> 2, ls = lane & 3;
    const int sw = ls ^ ((lr >> 1) & 3);
    const ush* gsrc = (w == 0) ? Wh : (w == 1) ? Wl : (w == 2) ? Xh : Xl;
    int sb[8];
    if (w < 2) {
#pragma unroll
        for (int t = 0; t < 8; ++t)
            sb[t] = (co0 + t * 16 + lr) * K + sw * 8;
    } else {
#pragma unroll
        for (int t = 0; t < 8; ++t) {
            const int p = n0 + t * 16 + lr;
            if (KS == 3) {
                const int bb = p >> logHW, hw = p & (HW - 1);
                const int oh = hw >> logS, ow = hw & (S - 1);
                sb[t] = ((bb * P + oh + 1) * P + ow + 1) * 256 + sw * 8;
            } else {
                sb[t] = p * Kin + sw * 8;
            }
        }
    }
    short* mypl = &lds[w][0][0];

    const int KC = K >> 5;
    const int slA = (l4 ^ ((l15 >> 1) & 3)) * 8;

    v4f acc[4][4] = {};

    for (int c = 0; c < KC; ++c) {
        int coff;
        if (w < 2 || KS == 1) {
            coff = c * 32;
        } else {
            const int rs = c >> 3;
            const int rr = (rs * 11) >> 5;
            const int ss = rs - 3 * rr;
            coff = ((rr - 1) * P + (ss - 1)) * 256 + (c & 7) * 32;
        }
#pragma unroll
        for (int t = 0; t < 8; ++t)
            gl_lds16(gsrc + (sb[t] + coff), mypl + t * 512);

        __syncthreads();

        v8s ah[4], al[4];
#pragma unroll
        for (int i = 0; i < 4; ++i) {
            ah[i] = *(const v8s*)&lds[0][wm * 64 + i * 16 + l15][slA];
            al[i] = *(const v8s*)&lds[1][wm * 64 + i * 16 + l15][slA];
        }
#pragma unroll
        for (int j = 0; j < 4; ++j) {
            const v8s bh = *(const v8s*)&lds[2][wn * 64 + j * 16 + l15][slA];
            const v8s bl = *(const v8s*)&lds[3][wn * 64 + j * 16 + l15][slA];
#pragma unroll
            for (int i = 0; i < 4; ++i) {
                acc[i][j] = __builtin_amdgcn_mfma_f32_16x16x32_bf16(ah[i], bh, acc[i][j], 0, 0, 0);
                acc[i][j] = __builtin_amdgcn_mfma_f32_16x16x32_bf16(ah[i], bl, acc[i][j], 0, 0, 0);
                acc[i][j] = __builtin_amdgcn_mfma_f32_16x16x32_bf16(al[i], bh, acc[i][j], 0, 0, 0);
            }
        }
        __syncthreads();
    }

#pragma unroll
    for (int i = 0; i < 4; ++i) {
        const int cob = wm * 64 + i * 16 + l4 * 4;
        const int co  = co0 + cob;
        float sc[4], sh[4];
#pragma unroll
        for (int e = 0; e < 4; ++e) {
            if (OM == 2) {
                sc[e] = 1.f;
                sh[e] = (co + e < Cout) ? bias[co + e] : 0.f;
            } else if (BNR) {
                const float inv = bng[co + e] * rsqrtf(bnv[co + e] + 1e-5f);
                sc[e] = inv;
                sh[e] = (bias[co + e] - bnm[co + e]) * inv + bnb[co + e];
            } else {
                sc[e] = 1.f; sh[e] = bias[co + e];
            }
        }
#pragma unroll
        for (int j = 0; j < 4; ++j) {
            const int ncol = n0 + wn * 64 + j * 16 + l15;
            const int b  = ncol >> logHW;
            const int hw = ncol & (HW - 1);
            float val[4];
#pragma unroll
            for (int e = 0; e < 4; ++e) {
                float x = acc[i][j][e] * sc[e] + sh[e];
                if (BNR) x = fmaxf(x, 0.f);
                val[e] = x;
            }
            if (OM == 2) {
#pragma unroll
                for (int e = 0; e < 4; ++e) {
                    const int c2 = co + e;
                    if (c2 < Cout) {
                        const int a = c2 / DD, cl = c2 - a * DD;
                        Yf[(size_t)((b + ibase) * TOTAL_ANCH + abase + hw * 9 + a) * 14
                           + coloff + cl] = val[e];
                    }
                }
            } else {
                int pidx;
                if (OM == 0) {
                    const int oh = hw >> logS, ow = hw & (S - 1);
                    pidx = (b * P + oh + 1) * P + ow + 1;
                } else {
                    pidx = ncol;
                }
                const int addr = pidx * 256 + co;
                ush hs[4], ls2[4];
#pragma unroll
                for (int e = 0; e < 4; ++e) splitf(val[e], hs[e], ls2[e]);
                *(uint2*)&Yh[addr] = make_uint2(hs[0] | ((unsigned)hs[1] << 16),
                                                hs[2] | ((unsigned)hs[3] << 16));
                *(uint2*)&Yl[addr] = make_uint2(ls2[0] | ((unsigned)ls2[1] << 16),
                                                ls2[2] | ((unsigned)ls2[3] << 16));
            }
        }
    }
}

// ---- prep / glue kernels -------------------------------------------------

__global__ void w3_prep(const float* __restrict__ W, ush* __restrict__ wh,
                        ush* __restrict__ wl, int total) {
    const int idx = blockIdx.x * 256 + threadIdx.x;
    if (idx >= total) return;
    const int co5 = idx / 2304;
    const int kk  = idx - co5 * 2304;
    const int rs = kk >> 8, ci = kk & 255;
    splitf(W[(co5 * 256 + ci) * 9 + rs], wh[idx], wl[idx]);
}

__global__ void w1_prep(const float* __restrict__ W, ush* __restrict__ wh,
                        ush* __restrict__ wl, int Cin, int Kp, int Cout, int total) {
    const int idx = blockIdx.x * 256 + threadIdx.x;
    if (idx >= total) return;
    const int co = idx / Kp;
    const int k  = idx - co * Kp;
    const float x = (co < Cout && k < Cin) ? W[co * Cin + k] : 0.f;
    splitf(x, wh[idx], wl[idx]);
}

__global__ void in_prep(const float* __restrict__ f, ush* __restrict__ xh,
                        ush* __restrict__ xl, int Cin, int Kp, int logHW, int total) {
    const int idx = blockIdx.x * 256 + threadIdx.x;
    if (idx >= total) return;
    const int c = idx % Kp;
    const int n = idx / Kp;
    const int b  = n >> logHW;
    const int hw = n & ((1 << logHW) - 1);
    const float x = (c < Cin) ? f[((b * Cin + c) << logHW) + hw] : 0.f;
    splitf(x, xh[idx], xl[idx]);
}

__global__ void upsample_hl(ush* __restrict__ fh, ush* __restrict__ fl,
                            const ush* __restrict__ ch, const ush* __restrict__ cl2,
                            int logSf, int total) {
    const int idx = blockIdx.x * 256 + threadIdx.x;
    if (idx >= total) return;
    const int ci = idx & 255;
    const int r  = idx >> 8;
    const int Sf = 1 << logSf;
    const int wf = r & (Sf - 1);
    const int hf = (r >> logSf) & (Sf - 1);
    const int b  = r >> (2 * logSf);
    const int Pf = Sf + 2, Pc = (Sf >> 1) + 2;
    const int fi = ((b * Pf + hf + 1) * Pf + wf + 1) * 256 + ci;
    const int cx = ((b * Pc + (hf >> 1) + 1) * Pc + (wf >> 1) + 1) * 256 + ci;
    const float x = bf2f(fh[fi]) + bf2f(fl[fi]) + bf2f(ch[cx]) + bf2f(cl2[cx]);
    splitf(x, fh[fi], fl[fi]);
}

__global__ void ring_zero(ush* __restrict__ yh, ush* __restrict__ yl, int S, int total) {
    const int idx = blockIdx.x * 256 + threadIdx.x;
    if (idx >= total) return;
    const int ci = idx & 255;
    const int r  = idx >> 8;
    const int P = S + 2;
    const int ring = 4 * P - 4;
    const int pr = r % ring;
    const int b  = r / ring;
    int ph, pw;
    if (pr < P)            { ph = 0;     pw = pr; }
    else if (pr < 2 * P)   { ph = P - 1; pw = pr - P; }
    else { const int q = pr - 2 * P; ph = 1 + (q >> 1); pw = (q & 1) ? (P - 1) : 0; }
    const int a = ((b * P + ph) * P + pw) * 256 + ci;
    yh[a] = 0; yl[a] = 0;
}

// ---------------------------------------------------------------------------

extern "C" void kernel_launch(void* const* d_in, const int* in_sizes, int n_in,
                              void* d_out, int out_size, void* d_ws, size_t ws_size,
                              hipStream_t stream)
{
    const float* f[5];     const float* lat_w[5];
    for (int i = 0; i < 5; ++i) f[i] = (const float*)d_in[i];
    for (int i = 0; i < 5; ++i) lat_w[i] = (const float*)d_in[5 + i];
    const float* lat_b  = (const float*)d_in[10];
    const float* fpn_w  = (const float*)d_in[11];
    const float* fpn_b  = (const float*)d_in[12];
    const float* cls_w1 = (const float*)d_in[13];
    const float* cls_b1 = (const float*)d_in[14];
    const float* cls_g  = (const float*)d_in[15];
    const float* cls_bt = (const float*)d_in[16];
    const float* cls_m  = (const float*)d_in[17];
    const float* cls_v  = (const float*)d_in[18];
    const float* cls_w2 = (const float*)d_in[19];
    const float* cls_b2 = (const float*)d_in[20];
    const float* reg_w1 = (const float*)d_in[21];
    const float* reg_b1 = (const float*)d_in[22];
    const float* reg_g  = (const float*)d_in[23];
    const float* reg_bt = (const float*)d_in[24];
    const float* reg_m  = (const float*)d_in[25];
    const float* reg_v  = (const float*)d_in[26];
    const float* reg_w2 = (const float*)d_in[27];
    const float* reg_b2 = (const float*)d_in[28];

    float* out = (float*)d_out;
    ush*   ws16 = (ush*)d_ws;

    static const int S_[5]     = {128, 64, 32, 16, 8};
    static const int logS_[5]  = {7, 6, 5, 4, 3};
    static const int logHW_[5] = {14, 12, 10, 8, 6};
    static const int HW_[5]    = {16384, 4096, 1024, 256, 64};
    static const int Cin_[5]   = {32, 48, 96, 136, 232};
    static const int Kp_[5]    = {32, 64, 96, 160, 256};
    static const int abase_[5] = {0, 147456, 184320, 193536, 195840};

    size_t off = 0;
    auto alloc = [&](size_t elems) {
        ush* p = ws16 + off;
        off += (elems + 63) & ~(size_t)63;
        return p;
    };

    // --- persistent: padded lateral planes (reused as head-conv1 tmp) ---
    ush *lat_h[5], *lat_l[5];
    for (int i = 0; i < 5; ++i) {
        const int P = S_[i] + 2;
        const size_t e = (size_t)2048 * P * P;   // 8 images * P*P * 256
        lat_h[i] = alloc(e); lat_l[i] = alloc(e);
    }
    const size_t lat_bytes = off * sizeof(ush);

    // --- shared transient arena ---
    const size_t ARENA_E = (size_t)2 * 4 * 130 * 130 * 256;
    ush* arena = alloc(ARENA_E);

    // --- weights (head conv2 padded to 128 co-rows for unguarded DMA) ---
    ush* fw_h = alloc((size_t)5 * 256 * 2304); ush* fw_l = alloc((size_t)5 * 256 * 2304);
    ush* cw_h = alloc(256 * 2304);             ush* cw_l = alloc(256 * 2304);
    ush* rw_h = alloc(256 * 2304);             ush* rw_l = alloc(256 * 2304);
    ush *lw_h[5], *lw_l[5];
    for (int i = 0; i < 5; ++i) { lw_h[i] = alloc(256 * Kp_[i]); lw_l[i] = alloc(256 * Kp_[i]); }
    ush* c2_h = alloc(128 * 256); ush* c2_l = alloc(128 * 256);
    ush* r2_h = alloc(128 * 256); ush* r2_l = alloc(128 * 256);

    hipMemsetAsync(ws16, 0, lat_bytes, stream);

    // --- weight prep ---
    {
        int t = 5 * 256 * 2304;
        w3_prep<<<dim3((t + 255) / 256), 256, 0, stream>>>(fpn_w, fw_h, fw_l, t);
        t = 256 * 2304;
        w3_prep<<<dim3((t + 255) / 256), 256, 0, stream>>>(cls_w1, cw_h, cw_l, t);
        w3_prep<<<dim3((t + 255) / 256), 256, 0, stream>>>(reg_w1, rw_h, rw_l, t);
        for (int i = 0; i < 5; ++i) {
            t = 256 * Kp_[i];
            w1_prep<<<dim3((t + 255) / 256), 256, 0, stream>>>(lat_w[i], lw_h[i], lw_l[i], Cin_[i], Kp_[i], 256, t);
        }
        t = 128 * 256;
        w1_prep<<<dim3((t + 255) / 256), 256, 0, stream>>>(cls_w2, c2_h, c2_l, 256, 256, 90, t);
        w1_prep<<<dim3((t + 255) / 256), 256, 0, stream>>>(reg_w2, r2_h, r2_l, 256, 256, 36, t);
    }

    // --- input conversion + lateral 1x1 convs ---
    for (int i = 0; i < 5; ++i) {
        const int N = 8 * HW_[i];
        const int t = N * Kp_[i];
        ush* xh = arena;
        ush* xl = arena + (size_t)N * Kp_[i];
        in_prep<<<dim3((t + 255) / 256), 256, 0, stream>>>(f[i], xh, xl, Cin_[i], Kp_[i], logHW_[i], t);
        conv_mfma<1, 0, false, 0><<<dim3(N / 128, 2), 256, 0, stream>>>(
            xh, xl, lw_h[i], lw_l[i], lat_b + i * 256,
            nullptr, nullptr, nullptr, nullptr,
            lat_h[i], lat_l[i], nullptr,
            Kp_[i], logS_[i], logHW_[i], Kp_[i], 256, 0, 0, 0);
    }

    // --- top-down pathway ---
    for (int i = 4; i >= 1; --i) {
        const int t = 8 * HW_[i - 1] * 256;
        upsample_hl<<<dim3((t + 255) / 256), 256, 0, stream>>>(
            lat_h[i - 1], lat_l[i - 1], lat_h[i], lat_l[i], logS_[i - 1], t);
    }

    // --- levels 1..4: whole-batch fpn + heads ---
    for (int i = 1; i < 5; ++i) {
        const int N = 8 * HW_[i];
        const int P = S_[i] + 2;
        ush* fpn_h = arena;
        ush* fpn_l = arena + (size_t)8 * P * P * 256;
        const int rt = 8 * (4 * P - 4) * 256;
        ring_zero<<<dim3((rt + 255) / 256), 256, 0, stream>>>(fpn_h, fpn_l, S_[i], rt);

        conv3p<0, false><<<dim3(N / 128), 512, 0, stream>>>(
            lat_h[i], lat_l[i], fw_h + (size_t)i * 256 * 2304, fw_l + (size_t)i * 256 * 2304,
            fpn_b + i * 256, nullptr, nullptr, nullptr, nullptr,
            fpn_h, fpn_l, logS_[i], logHW_[i]);

        conv3p<1, true><<<dim3(N / 128), 512, 0, stream>>>(
            fpn_h, fpn_l, cw_h, cw_l, cls_b1, cls_g, cls_bt, cls_m, cls_v,
            lat_h[i], lat_l[i], logS_[i], logHW_[i]);
        conv_mfma<1, 2, false, 10><<<dim3(N / 128, 1), 256, 0, stream>>>(
            lat_h[i], lat_l[i], c2_h, c2_l, cls_b2,
            nullptr, nullptr, nullptr, nullptr, nullptr, nullptr, out,
            256, logS_[i], logHW_[i], 256, 90, abase_[i], 4, 0);

        conv3p<1, true><<<dim3(N / 128), 512, 0, stream>>>(
            fpn_h, fpn_l, rw_h, rw_l, reg_b1, reg_g, reg_bt, reg_m, reg_v,
            lat_h[i], lat_l[i], logS_[i], logHW_[i]);
        conv_mfma<1, 2, false, 4><<<dim3(N / 128, 1), 256, 0, stream>>>(
            lat_h[i], lat_l[i], r2_h, r2_l, reg_b2,
            nullptr, nullptr, nullptr, nullptr, nullptr, nullptr, out,
            256, logS_[i], logHW_[i], 256, 36, abase_[i], 0, 0);
    }

    // --- level 0: two 4-image groups ---
    {
        const int P = 130;
        const size_t padg = (size_t)4 * P * P * 256;     // padded, 4 images
        const size_t unpg = (size_t)4 * 16384 * 256;     // unpadded, 4 images
        for (int g = 0; g < 2; ++g) {
            const int N = 4 * 16384;                     // 65536 pixels/group
            ush* fpn_h = arena;
            ush* fpn_l = arena + padg;
            ush* lat0p_h = lat_h[0] + (size_t)g * padg;
            ush* lat0p_l = lat_l[0] + (size_t)g * padg;
            ush* tmp_h   = lat_h[0] + (size_t)g * unpg;
            ush* tmp_l   = lat_l[0] + (size_t)g * unpg;
            const int rt = 4 * (4 * P - 4) * 256;
            ring_zero<<<dim3((rt + 255) / 256), 256, 0, stream>>>(fpn_h, fpn_l, 128, rt);

            conv3p<0, false><<<dim3(N / 128), 512, 0, stream>>>(
                lat0p_h, lat0p_l, fw_h, fw_l, fpn_b,
                nullptr, nullptr, nullptr, nullptr,
                fpn_h, fpn_l, 7, 14);

            conv3p<1, true><<<dim3(N / 128), 512, 0, stream>>>(
                fpn_h, fpn_l, cw_h, cw_l, cls_b1, cls_g, cls_bt, cls_m, cls_v,
                tmp_h, tmp_l, 7, 14);
            conv_mfma<1, 2, false, 10><<<dim3(N / 128, 1), 256, 0, stream>>>(
                tmp_h, tmp_l, c2_h, c2_l, cls_b2,
                nullptr, nullptr, nullptr, nullptr, nullptr, nullptr, out,
                256, 7, 14, 256, 90, 0, 4, 4 * g);

            conv3p<1, true><<<dim3(N / 128), 512, 0, stream>>>(
                fpn_h, fpn_l, rw_h, rw_l, reg_b1, reg_g, reg_bt, reg_m, reg_v,
                tmp_h, tmp_l, 7, 14);
            conv_mfma<1, 2, false, 4><<<dim3(N / 128, 1), 256, 0, stream>>>(
                tmp_h, tmp_l, r2_h, r2_l, reg_b2,
                nullptr, nullptr, nullptr, nullptr, nullptr, nullptr, out,
                256, 7, 14, 256, 36, 0, 0, 4 * g);
        }
    }
}

// Round 4
// 2727.263 us; speedup vs baseline: 1.3005x; 1.3005x over previous
//
#include <hip/hip_runtime.h>

// ---------------------------------------------------------------------------
// EfficientDet head on MFMA (gfx950), split-bf16 (hi+lo) fp32-accurate GEMM.
// All convs = implicit GEMM: C[co][n] = W[co][k] * Im2col[k][n].
// Activations: NHWC bf16 hi/lo planes; 3x3 inputs spatially zero-padded P=S+2.
// K order for 3x3: k = (r*3+s)*256 + ci  (tap-major -> contiguous ci chunks).
// 3 MFMAs per tile-pair: AhiBhi + AhiBlo + AloBhi  (error ~2^-17 relative).
//
// R4: dispatch consolidation. Per conv3p block the 72-chunk K-loop is a fixed
// ~128 us, so the twelve small lvl1-4 dispatches (256/64/16/4 blocks) wasted
// ~1.1 ms of idle-CU time. Now: all 4 levels' fpn planes live in the arena at
// once (24.3M elems <= 34.6M) and lvl1-4 run as ONE 340-block dispatch per
// conv (fpn / cls1 / reg1), with per-block level lookup (conv3f table).
// Scatter head-conv2s fused the same way (conv_sf). Level-0 path unchanged
// (512-block dispatches are already packed) and uses the same kernels with
// 1-entry tables. Inner loop = R2's proven 2-phase counted-vmcnt schedule
// (R3's reg-dbuf regressed; reverted).
// ---------------------------------------------------------------------------

typedef unsigned short ush;
typedef __attribute__((ext_vector_type(8))) short v8s;
typedef __attribute__((ext_vector_type(4))) float v4f;

constexpr int TOTAL_ANCH = 196416;  // 9 * (128^2+64^2+32^2+16^2+8^2)

#define VMW(n) asm volatile("s_waitcnt vmcnt(" #n ")" ::: "memory")
#define LGW()  asm volatile("s_waitcnt lgkmcnt(0)" ::: "memory")

__device__ __forceinline__ ush f2bf(float x) {
    unsigned u = __builtin_bit_cast(unsigned, x);
    u += 0x7FFFu + ((u >> 16) & 1u);
    return (ush)(u >> 16);
}
__device__ __forceinline__ float bf2f(ush h) {
    unsigned u = ((unsigned)h) << 16;
    return __builtin_bit_cast(float, u);
}
__device__ __forceinline__ void splitf(float x, ush& hi, ush& lo) {
    hi = f2bf(x);
    lo = f2bf(x - bf2f(hi));
}

__device__ __forceinline__ void gl_lds16(const ush* g, short* l) {
    __builtin_amdgcn_global_load_lds(
        (const __attribute__((address_space(1))) unsigned*)(const void*)g,
        (__attribute__((address_space(3))) unsigned*)l, 16, 0, 0);
}

// per-level work descriptors (kernel args by value)
struct Lvl3 {
    const ush* xh; const ush* xl;    // input planes (padded NHWC hi/lo)
    ush* yh; ush* yl;                // output planes
    const float* bias;
    int wofs, logS, logHW, bstart;   // weight elem offset; block range start
};
struct Tab3 { Lvl3 l[4]; };

struct LvlS {
    const ush* xh; const ush* xl;    // input planes (unpadded NHWC hi/lo)
    int abase, logHW, bstart, ibase;
};
struct TabS { LvlS l[4]; };

// ---------------------------------------------------------------------------
// Deep-pipelined 3x3 conv, fused multi-level: K=2304, Cout=256, 128 px/block.
// 8 waves: wm=w&3 (co quarter, 64 rows), wn=w>>2 (px half, 64 cols).
// LDS per buffer (48KB): Ah[256][32] | Al | Bh[128][32] | Bl  (shorts).
// Staging roles: waves 0-1 Ah, 2-3 Al, 4-5 Bh, 6-7 Bl; A-waves 8 DMA/chunk,
// B-waves 4.  Slot swizzle (both sides): seg(row,slot) = slot ^ ((row>>1)&3).
// Triple-buffered, counted vmcnt(8/4) at chunk boundaries (R2 schedule).
// OM: 0 = padded NHWC hi/lo out; 1 = unpadded NHWC hi/lo out.  BNR: BN+ReLU.
// ---------------------------------------------------------------------------
template <int OM, bool BNR>
__global__ __launch_bounds__(512, 2)
void conv3f(Tab3 T,
            const ush* __restrict__ Wh, const ush* __restrict__ Wl,
            const float* __restrict__ bng, const float* __restrict__ bnb,
            const float* __restrict__ bnm, const float* __restrict__ bnv)
{
    constexpr int K = 2304, KC = 72;

    // bijective XCD-aware swizzle on the 1-D grid
    const int nwg = gridDim.x;
    const int flat = blockIdx.x;
    const int xcd = flat & 7, sidx = flat >> 3;
    const int q = nwg >> 3, r8 = nwg & 7;
    const int nf = (xcd < r8 ? xcd * (q + 1) : r8 * (q + 1) + (xcd - r8) * q) + sidx;

    // level lookup
    int li = 0;
    if (nf >= T.l[1].bstart) li = 1;
    if (nf >= T.l[2].bstart) li = 2;
    if (nf >= T.l[3].bstart) li = 3;
    const int logS = T.l[li].logS, logHW = T.l[li].logHW;
    const int S = 1 << logS, HW = 1 << logHW, P = S + 2;
    const ush* __restrict__ Xh = T.l[li].xh;
    const ush* __restrict__ Xl = T.l[li].xl;
    ush* __restrict__ Yh = T.l[li].yh;
    ush* __restrict__ Yl = T.l[li].yl;
    const float* __restrict__ bias = T.l[li].bias;
    const int wofs = T.l[li].wofs;
    const int n0 = (nf - T.l[li].bstart) * 128;

    __shared__ __align__(16) short lds[3][24576];
    // per buffer offsets (shorts): Ah 0 | Al 8192 | Bh 16384 | Bl 20480

    const int tid = threadIdx.x;
    const int lane = tid & 63, w = tid >> 6;
    const int wm = w & 3, wn = w >> 2;
    const int l15 = lane & 15, l4 = lane >> 4;
    const int lr = lane >> 2, ls = lane & 3;
    const int sw = ls ^ ((lr >> 1) & 3);

    const int role = w >> 1, part = w & 1;   // role 0:Ah 1:Al 2:Bh 3:Bl
    const ush* gsrc = role == 0 ? Wh + wofs : role == 1 ? Wl + wofs
                    : role == 2 ? Xh : Xl;
    const int poff = role < 2 ? role * 8192 : 16384 + (role - 2) * 4096;

    int sb[8];
    if (role < 2) {
#pragma unroll
        for (int t = 0; t < 8; ++t)
            sb[t] = (part * 128 + t * 16 + lr) * K + sw * 8;
    } else {
#pragma unroll
        for (int t = 0; t < 4; ++t) {
            const int p = n0 + part * 64 + t * 16 + lr;
            const int bb = p >> logHW, hw = p & (HW - 1);
            const int oh = hw >> logS, ow = hw & (S - 1);
            sb[t] = ((bb * P + oh + 1) * P + ow + 1) * 256 + sw * 8;
        }
    }

    // stage half h of chunk c into buffer u (A: 4 loads, B: 2 loads)
    auto stage = [&](int u, int c, int h) {
        short* db = &lds[0][0] + u * 24576 + poff;
        if (role < 2) {
            const int coff = c * 32;
#pragma unroll
            for (int k = 0; k < 4; ++k) {
                const int t = h * 4 + k;
                gl_lds16(gsrc + (sb[t] + coff), db + part * 4096 + t * 512);
            }
        } else {
            const int rs = c >> 3;             // tap 0..8 (uniform)
            const int rr = (rs * 11) >> 5;     // rs / 3
            const int ss = rs - 3 * rr;
            const int coff = ((rr - 1) * P + (ss - 1)) * 256 + (c & 7) * 32;
#pragma unroll
            for (int k = 0; k < 2; ++k) {
                const int t = h * 2 + k;
                gl_lds16(gsrc + (sb[t] + coff), db + part * 2048 + t * 512);
            }
        }
    };

    // fragment read offsets (shorts)
    const int slr = (l4 ^ ((l15 >> 1) & 3)) * 8;
    int aoff[4], boff[4];
#pragma unroll
    for (int i = 0; i < 4; ++i) aoff[i] = (wm * 64 + i * 16 + l15) * 32 + slr;
#pragma unroll
    for (int j = 0; j < 4; ++j) boff[j] = (wn * 64 + j * 16 + l15) * 32 + slr;

    v4f acc[4][4] = {};

    // prologue: chunks 0,1 fully staged; drain to "chunk 0 arrived"
    stage(0, 0, 0); stage(0, 0, 1);
    stage(1, 1, 0); stage(1, 1, 1);
    if (role < 2) { VMW(8); } else { VMW(4); }
    __builtin_amdgcn_sched_barrier(0);
    __builtin_amdgcn_s_barrier();

    int cur = 0, nst = 2;
    for (int c = 0; c < KC; ++c) {
        const bool pf = (c + 2) < KC;
        const short* bb = &lds[0][0] + cur * 24576;

        // ---- phase 0: all A frags + B cols 0,1 ----
        v8s ah[4], al[4], bh[4], bl[4];
#pragma unroll
        for (int i = 0; i < 4; ++i) {
            ah[i] = *(const v8s*)(bb + aoff[i]);
            al[i] = *(const v8s*)(bb + 8192 + aoff[i]);
        }
#pragma unroll
        for (int j = 0; j < 2; ++j) {
            bh[j] = *(const v8s*)(bb + 16384 + boff[j]);
            bl[j] = *(const v8s*)(bb + 20480 + boff[j]);
        }
        if (pf) stage(nst, c + 2, 0);
        __builtin_amdgcn_s_barrier();
        LGW();
        __builtin_amdgcn_sched_barrier(0);
        __builtin_amdgcn_s_setprio(1);
#pragma unroll
        for (int j = 0; j < 2; ++j)
#pragma unroll
            for (int i = 0; i < 4; ++i) {
                acc[i][j] = __builtin_amdgcn_mfma_f32_16x16x32_bf16(ah[i], bh[j], acc[i][j], 0, 0, 0);
                acc[i][j] = __builtin_amdgcn_mfma_f32_16x16x32_bf16(ah[i], bl[j], acc[i][j], 0, 0, 0);
                acc[i][j] = __builtin_amdgcn_mfma_f32_16x16x32_bf16(al[i], bh[j], acc[i][j], 0, 0, 0);
            }
        __builtin_amdgcn_s_setprio(0);
        __builtin_amdgcn_s_barrier();

        // ---- phase 1: B cols 2,3 ----
#pragma unroll
        for (int j = 2; j < 4; ++j) {
            bh[j] = *(const v8s*)(bb + 16384 + boff[j]);
            bl[j] = *(const v8s*)(bb + 20480 + boff[j]);
        }
        if (pf) stage(nst, c + 2, 1);
        __builtin_amdgcn_s_barrier();
        LGW();
        __builtin_amdgcn_sched_barrier(0);
        __builtin_amdgcn_s_setprio(1);
#pragma unroll
        for (int j = 2; j < 4; ++j)
#pragma unroll
            for (int i = 0; i < 4; ++i) {
                acc[i][j] = __builtin_amdgcn_mfma_f32_16x16x32_bf16(ah[i], bh[j], acc[i][j], 0, 0, 0);
                acc[i][j] = __builtin_amdgcn_mfma_f32_16x16x32_bf16(ah[i], bl[j], acc[i][j], 0, 0, 0);
                acc[i][j] = __builtin_amdgcn_mfma_f32_16x16x32_bf16(al[i], bh[j], acc[i][j], 0, 0, 0);
            }
        __builtin_amdgcn_s_setprio(0);
        // counted boundary drain: own outstanding after wait = chunk c+2's
        // loads only (A:8, B:4); next chunk's reads gated by the barrier.
        if (pf) { if (role < 2) { VMW(8); } else { VMW(4); } }
        else    { VMW(0); }
        __builtin_amdgcn_sched_barrier(0);
        __builtin_amdgcn_s_barrier();

        cur = cur == 2 ? 0 : cur + 1;
        nst = nst == 2 ? 0 : nst + 1;
    }

    // ---- epilogue: col = lane&15 (pixel), row = (lane>>4)*4+e (co) ----
#pragma unroll
    for (int i = 0; i < 4; ++i) {
        const int co = wm * 64 + i * 16 + l4 * 4;
        float sc[4], sh[4];
#pragma unroll
        for (int e = 0; e < 4; ++e) {
            if (BNR) {
                const float inv = bng[co + e] * rsqrtf(bnv[co + e] + 1e-5f);
                sc[e] = inv;
                sh[e] = (bias[co + e] - bnm[co + e]) * inv + bnb[co + e];
            } else { sc[e] = 1.f; sh[e] = bias[co + e]; }
        }
#pragma unroll
        for (int j = 0; j < 4; ++j) {
            const int ncol = n0 + wn * 64 + j * 16 + l15;
            const int b  = ncol >> logHW;
            const int hw = ncol & (HW - 1);
            float val[4];
#pragma unroll
            for (int e = 0; e < 4; ++e) {
                float x = acc[i][j][e] * sc[e] + sh[e];
                if (BNR) x = fmaxf(x, 0.f);
                val[e] = x;
            }
            int pidx;
            if (OM == 0) {
                const int oh = hw >> logS, ow = hw & (S - 1);
                pidx = (b * P + oh + 1) * P + ow + 1;
            } else {
                pidx = ncol;
            }
            const int addr = pidx * 256 + co;
            ush hs[4], ls2[4];
#pragma unroll
            for (int e = 0; e < 4; ++e) splitf(val[e], hs[e], ls2[e]);
            *(uint2*)&Yh[addr] = make_uint2(hs[0] | ((unsigned)hs[1] << 16),
                                            hs[2] | ((unsigned)hs[3] << 16));
            *(uint2*)&Yl[addr] = make_uint2(ls2[0] | ((unsigned)ls2[1] << 16),
                                            ls2[2] | ((unsigned)ls2[3] << 16));
        }
    }
}

// ---------------------------------------------------------------------------
// Fused scatter head-conv2 (1x1, K=256, Cout=9*DD, fp32 scatter epilogue).
// 4 waves, 128 px/block, co0 = 0 (Cout <= 128; weights zero-padded to 128).
// Same R1 global_load_lds staging + slot swizzle.
// ---------------------------------------------------------------------------
template <int DD>
__global__ __launch_bounds__(256, 3)
void conv_sf(TabS T, const ush* __restrict__ Wh, const ush* __restrict__ Wl,
             const float* __restrict__ bias, float* __restrict__ out)
{
    constexpr int K = 256, KC = 8, Cout = 9 * DD;
    constexpr int coloff = (DD == 10) ? 4 : 0;

    const int nwg = gridDim.x;
    const int flat = blockIdx.x;
    const int xcd = flat & 7, sidx = flat >> 3;
    const int q = nwg >> 3, r8 = nwg & 7;
    const int nf = (xcd < r8 ? xcd * (q + 1) : r8 * (q + 1) + (xcd - r8) * q) + sidx;

    int li = 0;
    if (nf >= T.l[1].bstart) li = 1;
    if (nf >= T.l[2].bstart) li = 2;
    if (nf >= T.l[3].bstart) li = 3;
    const int logHW = T.l[li].logHW;
    const int HW = 1 << logHW;
    const ush* __restrict__ Xh = T.l[li].xh;
    const ush* __restrict__ Xl = T.l[li].xl;
    const int abase = T.l[li].abase, ibase = T.l[li].ibase;
    const int n0 = (nf - T.l[li].bstart) * 128;

    __shared__ short lds[4][128][32];

    const int tid = threadIdx.x;
    const int lane = tid & 63;
    const int w = tid >> 6;
    const int wm = w & 1, wn = w >> 1;
    const int l15 = lane & 15, l4 = lane >> 4;
    const int lr = lane >> 2, ls = lane & 3;
    const int sw = ls ^ ((lr >> 1) & 3);
    const ush* gsrc = (w == 0) ? Wh : (w == 1) ? Wl : (w == 2) ? Xh : Xl;
    int sb[8];
    if (w < 2) {
#pragma unroll
        for (int t = 0; t < 8; ++t)
            sb[t] = (t * 16 + lr) * K + sw * 8;
    } else {
#pragma unroll
        for (int t = 0; t < 8; ++t)
            sb[t] = (n0 + t * 16 + lr) * 256 + sw * 8;
    }
    short* mypl = &lds[w][0][0];
    const int slA = (l4 ^ ((l15 >> 1) & 3)) * 8;

    v4f acc[4][4] = {};

    for (int c = 0; c < KC; ++c) {
        const int coff = c * 32;
#pragma unroll
        for (int t = 0; t < 8; ++t)
            gl_lds16(gsrc + (sb[t] + coff), mypl + t * 512);

        __syncthreads();

        v8s ah[4], al[4];
#pragma unroll
        for (int i = 0; i < 4; ++i) {
            ah[i] = *(const v8s*)&lds[0][wm * 64 + i * 16 + l15][slA];
            al[i] = *(const v8s*)&lds[1][wm * 64 + i * 16 + l15][slA];
        }
#pragma unroll
        for (int j = 0; j < 4; ++j) {
            const v8s bh = *(const v8s*)&lds[2][wn * 64 + j * 16 + l15][slA];
            const v8s bl = *(const v8s*)&lds[3][wn * 64 + j * 16 + l15][slA];
#pragma unroll
            for (int i = 0; i < 4; ++i) {
                acc[i][j] = __builtin_amdgcn_mfma_f32_16x16x32_bf16(ah[i], bh, acc[i][j], 0, 0, 0);
                acc[i][j] = __builtin_amdgcn_mfma_f32_16x16x32_bf16(ah[i], bl, acc[i][j], 0, 0, 0);
                acc[i][j] = __builtin_amdgcn_mfma_f32_16x16x32_bf16(al[i], bh, acc[i][j], 0, 0, 0);
            }
        }
        __syncthreads();
    }

#pragma unroll
    for (int i = 0; i < 4; ++i) {
        const int co = wm * 64 + i * 16 + l4 * 4;
        float sh[4];
#pragma unroll
        for (int e = 0; e < 4; ++e)
            sh[e] = (co + e < Cout) ? bias[co + e] : 0.f;
#pragma unroll
        for (int j = 0; j < 4; ++j) {
            const int ncol = n0 + wn * 64 + j * 16 + l15;
            const int b  = ncol >> logHW;
            const int hw = ncol & (HW - 1);
#pragma unroll
            for (int e = 0; e < 4; ++e) {
                const int c2 = co + e;
                if (c2 < Cout) {
                    const float val = acc[i][j][e] + sh[e];
                    const int a = c2 / DD, cl = c2 - a * DD;
                    out[(size_t)((b + ibase) * TOTAL_ANCH + abase + hw * 9 + a) * 14
                        + coloff + cl] = val;
                }
            }
        }
    }
}

// ---------------------------------------------------------------------------
// R1 128^2 kernel — retained for the 1x1 lateral convs (KS=1, OM=0).
// ---------------------------------------------------------------------------
template <int KS, int OM, bool BNR, int DD>
__global__ __launch_bounds__(256, 3)
void conv_mfma(const ush* __restrict__ Xh, const ush* __restrict__ Xl,
               const ush* __restrict__ Wh, const ush* __restrict__ Wl,
               const float* __restrict__ bias,
               ush* __restrict__ Yh, ush* __restrict__ Yl,
               int K, int logS, int logHW, int Kin)
{
    const int tid = threadIdx.x;

    const int nwg  = gridDim.x * gridDim.y;
    const int flat = blockIdx.y * gridDim.x + blockIdx.x;
    const int xcd = flat & 7, sidx = flat >> 3;
    const int q = nwg >> 3, r8 = nwg & 7;
    const int nf = (xcd < r8 ? xcd * (q + 1) : r8 * (q + 1) + (xcd - r8) * q) + sidx;
    int bx, by;
    if (gridDim.y == 2) { bx = nf >> 1; by = nf & 1; }
    else                { bx = nf;      by = 0;      }

    const int n0  = bx * 128;
    const int co0 = by * 128;
    const int S = 1 << logS, HW = 1 << logHW, P = S + 2;

    __shared__ short lds[4][128][32];

    const int lane = tid & 63;
    const int w = tid >> 6;
    const int wm = w & 1, wn = w >> 1;
    const int l15 = lane & 15, l4 = lane >> 4;

    const int lr = lane >> 2, ls = lane & 3;
    const int sw = ls ^ ((lr >> 1) & 3);
    const ush* gsrc = (w == 0) ? Wh : (w == 1) ? Wl : (w == 2) ? Xh : Xl;
    int sb[8];
    if (w < 2) {
#pragma unroll
        for (int t = 0; t < 8; ++t)
            sb[t] = (co0 + t * 16 + lr) * K + sw * 8;
    } else {
#pragma unroll
        for (int t = 0; t < 8; ++t) {
            const int p = n0 + t * 16 + lr;
            sb[t] = p * Kin + sw * 8;
        }
    }
    short* mypl = &lds[w][0][0];

    const int KC = K >> 5;
    const int slA = (l4 ^ ((l15 >> 1) & 3)) * 8;

    v4f acc[4][4] = {};

    for (int c = 0; c < KC; ++c) {
        const int coff = c * 32;
#pragma unroll
        for (int t = 0; t < 8; ++t)
            gl_lds16(gsrc + (sb[t] + coff), mypl + t * 512);

        __syncthreads();

        v8s ah[4], al[4];
#pragma unroll
        for (int i = 0; i < 4; ++i) {
            ah[i] = *(const v8s*)&lds[0][wm * 64 + i * 16 + l15][slA];
            al[i] = *(const v8s*)&lds[1][wm * 64 + i * 16 + l15][slA];
        }
#pragma unroll
        for (int j = 0; j < 4; ++j) {
            const v8s bh = *(const v8s*)&lds[2][wn * 64 + j * 16 + l15][slA];
            const v8s bl = *(const v8s*)&lds[3][wn * 64 + j * 16 + l15][slA];
#pragma unroll
            for (int i = 0; i < 4; ++i) {
                acc[i][j] = __builtin_amdgcn_mfma_f32_16x16x32_bf16(ah[i], bh, acc[i][j], 0, 0, 0);
                acc[i][j] = __builtin_amdgcn_mfma_f32_16x16x32_bf16(ah[i], bl, acc[i][j], 0, 0, 0);
                acc[i][j] = __builtin_amdgcn_mfma_f32_16x16x32_bf16(al[i], bh, acc[i][j], 0, 0, 0);
            }
        }
        __syncthreads();
    }

#pragma unroll
    for (int i = 0; i < 4; ++i) {
        const int cob = wm * 64 + i * 16 + l4 * 4;
        const int co  = co0 + cob;
        float sh[4];
#pragma unroll
        for (int e = 0; e < 4; ++e) sh[e] = bias[co + e];
#pragma unroll
        for (int j = 0; j < 4; ++j) {
            const int ncol = n0 + wn * 64 + j * 16 + l15;
            const int b  = ncol >> logHW;
            const int hw = ncol & (HW - 1);
            float val[4];
#pragma unroll
            for (int e = 0; e < 4; ++e) val[e] = acc[i][j][e] + sh[e];
            int pidx;
            if (OM == 0) {
                const int oh = hw >> logS, ow = hw & (S - 1);
                pidx = (b * P + oh + 1) * P + ow + 1;
            } else {
                pidx = ncol;
            }
            const int addr = pidx * 256 + co;
            ush hs[4], ls2[4];
#pragma unroll
            for (int e = 0; e < 4; ++e) splitf(val[e], hs[e], ls2[e]);
            *(uint2*)&Yh[addr] = make_uint2(hs[0] | ((unsigned)hs[1] << 16),
                                            hs[2] | ((unsigned)hs[3] << 16));
            *(uint2*)&Yl[addr] = make_uint2(ls2[0] | ((unsigned)ls2[1] << 16),
                                            ls2[2] | ((unsigned)ls2[3] << 16));
        }
    }
}

// ---- prep / glue kernels -------------------------------------------------

__global__ void w3_prep(const float* __restrict__ W, ush* __restrict__ wh,
                        ush* __restrict__ wl, int total) {
    const int idx = blockIdx.x * 256 + threadIdx.x;
    if (idx >= total) return;
    const int co5 = idx / 2304;
    const int kk  = idx - co5 * 2304;
    const int rs = kk >> 8, ci = kk & 255;
    splitf(W[(co5 * 256 + ci) * 9 + rs], wh[idx], wl[idx]);
}

__global__ void w1_prep(const float* __restrict__ W, ush* __restrict__ wh,
                        ush* __restrict__ wl, int Cin, int Kp, int Cout, int total) {
    const int idx = blockIdx.x * 256 + threadIdx.x;
    if (idx >= total) return;
    const int co = idx / Kp;
    const int k  = idx - co * Kp;
    const float x = (co < Cout && k < Cin) ? W[co * Cin + k] : 0.f;
    splitf(x, wh[idx], wl[idx]);
}

__global__ void in_prep(const float* __restrict__ f, ush* __restrict__ xh,
                        ush* __restrict__ xl, int Cin, int Kp, int logHW, int total) {
    const int idx = blockIdx.x * 256 + threadIdx.x;
    if (idx >= total) return;
    const int c = idx % Kp;
    const int n = idx / Kp;
    const int b  = n >> logHW;
    const int hw = n & ((1 << logHW) - 1);
    const float x = (c < Cin) ? f[((b * Cin + c) << logHW) + hw] : 0.f;
    splitf(x, xh[idx], xl[idx]);
}

__global__ void upsample_hl(ush* __restrict__ fh, ush* __restrict__ fl,
                            const ush* __restrict__ ch, const ush* __restrict__ cl2,
                            int logSf, int total) {
    const int idx = blockIdx.x * 256 + threadIdx.x;
    if (idx >= total) return;
    const int ci = idx & 255;
    const int r  = idx >> 8;
    const int Sf = 1 << logSf;
    const int wf = r & (Sf - 1);
    const int hf = (r >> logSf) & (Sf - 1);
    const int b  = r >> (2 * logSf);
    const int Pf = Sf + 2, Pc = (Sf >> 1) + 2;
    const int fi = ((b * Pf + hf + 1) * Pf + wf + 1) * 256 + ci;
    const int cx = ((b * Pc + (hf >> 1) + 1) * Pc + (wf >> 1) + 1) * 256 + ci;
    const float x = bf2f(fh[fi]) + bf2f(fl[fi]) + bf2f(ch[cx]) + bf2f(cl2[cx]);
    splitf(x, fh[fi], fl[fi]);
}

__global__ void ring_zero(ush* __restrict__ yh, ush* __restrict__ yl, int S, int total) {
    const int idx = blockIdx.x * 256 + threadIdx.x;
    if (idx >= total) return;
    const int ci = idx & 255;
    const int r  = idx >> 8;
    const int P = S + 2;
    const int ring = 4 * P - 4;
    const int pr = r % ring;
    const int b  = r / ring;
    int ph, pw;
    if (pr < P)            { ph = 0;     pw = pr; }
    else if (pr < 2 * P)   { ph = P - 1; pw = pr - P; }
    else { const int q = pr - 2 * P; ph = 1 + (q >> 1); pw = (q & 1) ? (P - 1) : 0; }
    const int a = ((b * P + ph) * P + pw) * 256 + ci;
    yh[a] = 0; yl[a] = 0;
}

// ---------------------------------------------------------------------------

extern "C" void kernel_launch(void* const* d_in, const int* in_sizes, int n_in,
                              void* d_out, int out_size, void* d_ws, size_t ws_size,
                              hipStream_t stream)
{
    const float* f[5];     const float* lat_w[5];
    for (int i = 0; i < 5; ++i) f[i] = (const float*)d_in[i];
    for (int i = 0; i < 5; ++i) lat_w[i] = (const float*)d_in[5 + i];
    const float* lat_b  = (const float*)d_in[10];
    const float* fpn_w  = (const float*)d_in[11];
    const float* fpn_b  = (const float*)d_in[12];
    const float* cls_w1 = (const float*)d_in[13];
    const float* cls_b1 = (const float*)d_in[14];
    const float* cls_g  = (const float*)d_in[15];
    const float* cls_bt = (const float*)d_in[16];
    const float* cls_m  = (const float*)d_in[17];
    const float* cls_v  = (const float*)d_in[18];
    const float* cls_w2 = (const float*)d_in[19];
    const float* cls_b2 = (const float*)d_in[20];
    const float* reg_w1 = (const float*)d_in[21];
    const float* reg_b1 = (const float*)d_in[22];
    const float* reg_g  = (const float*)d_in[23];
    const float* reg_bt = (const float*)d_in[24];
    const float* reg_m  = (const float*)d_in[25];
    const float* reg_v  = (const float*)d_in[26];
    const float* reg_w2 = (const float*)d_in[27];
    const float* reg_b2 = (const float*)d_in[28];

    float* out = (float*)d_out;
    ush*   ws16 = (ush*)d_ws;

    static const int S_[5]     = {128, 64, 32, 16, 8};
    static const int logS_[5]  = {7, 6, 5, 4, 3};
    static const int logHW_[5] = {14, 12, 10, 8, 6};
    static const int HW_[5]    = {16384, 4096, 1024, 256, 64};
    static const int Cin_[5]   = {32, 48, 96, 136, 232};
    static const int Kp_[5]    = {32, 64, 96, 160, 256};
    static const int abase_[5] = {0, 147456, 184320, 193536, 195840};
    constexpr int BIG = 0x7fffffff;

    size_t off = 0;
    auto alloc = [&](size_t elems) {
        ush* p = ws16 + off;
        off += (elems + 63) & ~(size_t)63;
        return p;
    };

    // --- persistent: padded lateral planes (reused as head-conv1 tmp) ---
    ush *lat_h[5], *lat_l[5];
    for (int i = 0; i < 5; ++i) {
        const int P = S_[i] + 2;
        const size_t e = (size_t)2048 * P * P;   // 8 images * P*P * 256
        lat_h[i] = alloc(e); lat_l[i] = alloc(e);
    }
    const size_t lat_bytes = off * sizeof(ush);

    // --- shared transient arena (69.2 MB) ---
    const size_t ARENA_E = (size_t)2 * 4 * 130 * 130 * 256;
    ush* arena = alloc(ARENA_E);

    // --- weights (head conv2 padded to 128 co-rows for unguarded DMA) ---
    ush* fw_h = alloc((size_t)5 * 256 * 2304); ush* fw_l = alloc((size_t)5 * 256 * 2304);
    ush* cw_h = alloc(256 * 2304);             ush* cw_l = alloc(256 * 2304);
    ush* rw_h = alloc(256 * 2304);             ush* rw_l = alloc(256 * 2304);
    ush *lw_h[5], *lw_l[5];
    for (int i = 0; i < 5; ++i) { lw_h[i] = alloc(256 * Kp_[i]); lw_l[i] = alloc(256 * Kp_[i]); }
    ush* c2_h = alloc(128 * 256); ush* c2_l = alloc(128 * 256);
    ush* r2_h = alloc(128 * 256); ush* r2_l = alloc(128 * 256);

    hipMemsetAsync(ws16, 0, lat_bytes, stream);

    // --- weight prep ---
    {
        int t = 5 * 256 * 2304;
        w3_prep<<<dim3((t + 255) / 256), 256, 0, stream>>>(fpn_w, fw_h, fw_l, t);
        t = 256 * 2304;
        w3_prep<<<dim3((t + 255) / 256), 256, 0, stream>>>(cls_w1, cw_h, cw_l, t);
        w3_prep<<<dim3((t + 255) / 256), 256, 0, stream>>>(reg_w1, rw_h, rw_l, t);
        for (int i = 0; i < 5; ++i) {
            t = 256 * Kp_[i];
            w1_prep<<<dim3((t + 255) / 256), 256, 0, stream>>>(lat_w[i], lw_h[i], lw_l[i], Cin_[i], Kp_[i], 256, t);
        }
        t = 128 * 256;
        w1_prep<<<dim3((t + 255) / 256), 256, 0, stream>>>(cls_w2, c2_h, c2_l, 256, 256, 90, t);
        w1_prep<<<dim3((t + 255) / 256), 256, 0, stream>>>(reg_w2, r2_h, r2_l, 256, 256, 36, t);
    }

    // --- input conversion + lateral 1x1 convs (arena transient) ---
    for (int i = 0; i < 5; ++i) {
        const int N = 8 * HW_[i];
        const int t = N * Kp_[i];
        ush* xh = arena;
        ush* xl = arena + (size_t)N * Kp_[i];
        in_prep<<<dim3((t + 255) / 256), 256, 0, stream>>>(f[i], xh, xl, Cin_[i], Kp_[i], logHW_[i], t);
        conv_mfma<1, 0, false, 0><<<dim3(N / 128, 2), 256, 0, stream>>>(
            xh, xl, lw_h[i], lw_l[i], lat_b + i * 256,
            lat_h[i], lat_l[i],
            Kp_[i], logS_[i], logHW_[i], Kp_[i]);
    }

    // --- top-down pathway ---
    for (int i = 4; i >= 1; --i) {
        const int t = 8 * HW_[i - 1] * 256;
        upsample_hl<<<dim3((t + 255) / 256), 256, 0, stream>>>(
            lat_h[i - 1], lat_l[i - 1], lat_h[i], lat_l[i], logS_[i - 1], t);
    }

    // --- levels 1..4 FUSED: all 4 fpn plane pairs resident in arena ---
    ush *fpn_h4[5], *fpn_l4[5];
    {
        size_t o = 0;
        for (int i = 1; i < 5; ++i) {
            const int P = S_[i] + 2;
            fpn_h4[i] = arena + o; o += (size_t)2048 * P * P;
            fpn_l4[i] = arena + o; o += (size_t)2048 * P * P;
        }
    }
    for (int i = 1; i < 5; ++i) {
        const int P = S_[i] + 2;
        const int rt = 8 * (4 * P - 4) * 256;
        ring_zero<<<dim3((rt + 255) / 256), 256, 0, stream>>>(fpn_h4[i], fpn_l4[i], S_[i], rt);
    }
    static const int bstart4[4] = {0, 256, 320, 336};   // 256+64+16+4 = 340

    {   // fused fpn conv (per-level weight slice + bias)
        Tab3 T{};
        for (int k = 0; k < 4; ++k) {
            const int i = k + 1;
            T.l[k] = Lvl3{ lat_h[i], lat_l[i], fpn_h4[i], fpn_l4[i],
                           fpn_b + i * 256, i * 256 * 2304,
                           logS_[i], logHW_[i], bstart4[k] };
        }
        conv3f<0, false><<<dim3(340), 512, 0, stream>>>(
            T, fw_h, fw_l, nullptr, nullptr, nullptr, nullptr);
    }
    {   // fused cls conv1 -> tmp (lat planes)
        Tab3 T{};
        for (int k = 0; k < 4; ++k) {
            const int i = k + 1;
            T.l[k] = Lvl3{ fpn_h4[i], fpn_l4[i], lat_h[i], lat_l[i],
                           cls_b1, 0, logS_[i], logHW_[i], bstart4[k] };
        }
        conv3f<1, true><<<dim3(340), 512, 0, stream>>>(
            T, cw_h, cw_l, cls_g, cls_bt, cls_m, cls_v);
    }
    {   // fused cls conv2 scatter
        TabS T{};
        for (int k = 0; k < 4; ++k) {
            const int i = k + 1;
            T.l[k] = LvlS{ lat_h[i], lat_l[i], abase_[i], logHW_[i], bstart4[k], 0 };
        }
        conv_sf<10><<<dim3(340), 256, 0, stream>>>(T, c2_h, c2_l, cls_b2, out);
    }
    {   // fused reg conv1 -> tmp
        Tab3 T{};
        for (int k = 0; k < 4; ++k) {
            const int i = k + 1;
            T.l[k] = Lvl3{ fpn_h4[i], fpn_l4[i], lat_h[i], lat_l[i],
                           reg_b1, 0, logS_[i], logHW_[i], bstart4[k] };
        }
        conv3f<1, true><<<dim3(340), 512, 0, stream>>>(
            T, rw_h, rw_l, reg_g, reg_bt, reg_m, reg_v);
    }
    {   // fused reg conv2 scatter
        TabS T{};
        for (int k = 0; k < 4; ++k) {
            const int i = k + 1;
            T.l[k] = LvlS{ lat_h[i], lat_l[i], abase_[i], logHW_[i], bstart4[k], 0 };
        }
        conv_sf<4><<<dim3(340), 256, 0, stream>>>(T, r2_h, r2_l, reg_b2, out);
    }

    // --- level 0: two 4-image groups (1-entry tables, packed 512-block) ---
    {
        const int P = 130;
        const size_t padg = (size_t)4 * P * P * 256;     // padded, 4 images
        const size_t unpg = (size_t)4 * 16384 * 256;     // unpadded, 4 images
        for (int g = 0; g < 2; ++g) {
            ush* fpn_h = arena;
            ush* fpn_l = arena + padg;
            ush* lat0p_h = lat_h[0] + (size_t)g * padg;
            ush* lat0p_l = lat_l[0] + (size_t)g * padg;
            ush* tmp_h   = lat_h[0] + (size_t)g * unpg;
            ush* tmp_l   = lat_l[0] + (size_t)g * unpg;
            const int rt = 4 * (4 * P - 4) * 256;
            ring_zero<<<dim3((rt + 255) / 256), 256, 0, stream>>>(fpn_h, fpn_l, 128, rt);

            Tab3 T{};
            T.l[0] = Lvl3{ lat0p_h, lat0p_l, fpn_h, fpn_l, fpn_b, 0, 7, 14, 0 };
            for (int k = 1; k < 4; ++k) T.l[k].bstart = BIG;
            conv3f<0, false><<<dim3(512), 512, 0, stream>>>(
                T, fw_h, fw_l, nullptr, nullptr, nullptr, nullptr);

            Tab3 Tc{};
            Tc.l[0] = Lvl3{ fpn_h, fpn_l, tmp_h, tmp_l, cls_b1, 0, 7, 14, 0 };
            for (int k = 1; k < 4; ++k) Tc.l[k].bstart = BIG;
            conv3f<1, true><<<dim3(512), 512, 0, stream>>>(
                Tc, cw_h, cw_l, cls_g, cls_bt, cls_m, cls_v);

            TabS Ts{};
            Ts.l[0] = LvlS{ tmp_h, tmp_l, 0, 14, 0, 4 * g };
            for (int k = 1; k < 4; ++k) Ts.l[k].bstart = BIG;
            conv_sf<10><<<dim3(512), 256, 0, stream>>>(Ts, c2_h, c2_l, cls_b2, out);

            Tab3 Tr{};
            Tr.l[0] = Lvl3{ fpn_h, fpn_l, tmp_h, tmp_l, reg_b1, 0, 7, 14, 0 };
            for (int k = 1; k < 4; ++k) Tr.l[k].bstart = BIG;
            conv3f<1, true><<<dim3(512), 512, 0, stream>>>(
                Tr, rw_h, rw_l, reg_g, reg_bt, reg_m, reg_v);

            TabS Tq{};
            Tq.l[0] = LvlS{ tmp_h, tmp_l, 0, 14, 0, 4 * g };
            for (int k = 1; k < 4; ++k) Tq.l[k].bstart = BIG;
            conv_sf<4><<<dim3(512), 256, 0, stream>>>(Tq, r2_h, r2_l, reg_b2, out);
        }
    }
}

// Round 5
// 2396.234 us; speedup vs baseline: 1.4802x; 1.1381x over previous
//
#include <hip/hip_runtime.h>

// ---------------------------------------------------------------------------
// EfficientDet head on MFMA (gfx950), split-bf16 (hi+lo) fp32-accurate GEMM.
// All convs = implicit GEMM: C[co][n] = W[co][k] * Im2col[k][n].
// Activations: NHWC bf16 hi/lo planes; 3x3 inputs spatially zero-padded P=S+2.
// K order for 3x3: k = (r*3+s)*256 + ci  (tap-major -> contiguous ci chunks).
// 3 MFMAs per tile-pair: AhiBhi + AhiBlo + AloBhi  (error ~2^-17 relative).
//
// R5: conv3g = 256co x 256px block tile (was 256x128), 8 waves each 128x64,
// BK=32, double-buffered 2x64KB LDS. Raises FLOP/LDS-byte 2x so LDS traffic
// (~320KB/chunk/CU ~ 2500cyc) hides under the MFMA floor (3072cyc). ONE
// barrier + ONE vmcnt(0) per chunk (drain covers DMA issued a chunk earlier).
// Four register-quadrant phases per chunk (m201 pattern): each phase
// {ds_read quadrant frags; lgkm0+sched_barrier; setprio1; 24 MFMA; setprio0}
// so reads overlap the previous quadrant's MFMAs; A/B frag regs reused
// across quadrants (A 8 v8s + B 4 v8s + acc 128 VGPR ~ 210 total).
// Level-0 group = 256 blocks = exactly one CU round; fused lvl1-4 = 170.
// 1x1 lateral + head-scatter convs keep the R1 128^2 global_load_lds kernel.
// ---------------------------------------------------------------------------

typedef unsigned short ush;
typedef __attribute__((ext_vector_type(8))) short v8s;
typedef __attribute__((ext_vector_type(4))) float v4f;

constexpr int TOTAL_ANCH = 196416;  // 9 * (128^2+64^2+32^2+16^2+8^2)

#define VMW(n) asm volatile("s_waitcnt vmcnt(" #n ")" ::: "memory")
#define LGW()  asm volatile("s_waitcnt lgkmcnt(0)" ::: "memory")

__device__ __forceinline__ ush f2bf(float x) {
    unsigned u = __builtin_bit_cast(unsigned, x);
    u += 0x7FFFu + ((u >> 16) & 1u);
    return (ush)(u >> 16);
}
__device__ __forceinline__ float bf2f(ush h) {
    unsigned u = ((unsigned)h) << 16;
    return __builtin_bit_cast(float, u);
}
__device__ __forceinline__ void splitf(float x, ush& hi, ush& lo) {
    hi = f2bf(x);
    lo = f2bf(x - bf2f(hi));
}

__device__ __forceinline__ void gl_lds16(const ush* g, short* l) {
    __builtin_amdgcn_global_load_lds(
        (const __attribute__((address_space(1))) unsigned*)(const void*)g,
        (__attribute__((address_space(3))) unsigned*)l, 16, 0, 0);
}

// per-level work descriptors (kernel args by value)
struct Lvl3 {
    const ush* xh; const ush* xl;    // input planes (padded NHWC hi/lo)
    ush* yh; ush* yl;                // output planes
    const float* bias;
    int wofs, logS, logHW, bstart;   // weight elem offset; block range start
};
struct Tab3 { Lvl3 l[4]; };

struct LvlS {
    const ush* xh; const ush* xl;    // input planes (unpadded NHWC hi/lo)
    int abase, logHW, bstart, ibase;
};
struct TabS { LvlS l[4]; };

// ---------------------------------------------------------------------------
// conv3g: deep 3x3 conv, fused multi-level. K=2304, Cout=256, 256 px/block.
// 8 waves: wm=w&1 (co half, 128 rows), wn=w>>1 (px quarter, 64 cols).
// LDS buffer (64KB): Ah[256][32] | Al | Bh[256][32] | Bl (8192 shorts each).
// Staging: role=w>>1 (0:Ah 1:Al 2:Bh 3:Bl), part=w&1 (128-row half); every
// wave 8 x gl_lds16 per chunk. Slot swizzle (both sides, proven 0-conflict):
// seg(row,slot) = slot ^ ((row>>1)&3).
// OM: 0 = padded NHWC hi/lo out; 1 = unpadded NHWC hi/lo out.  BNR: BN+ReLU.
// ---------------------------------------------------------------------------
#define MFMA3(AH, AL, BH, BL, ACC)                                            \
    ACC = __builtin_amdgcn_mfma_f32_16x16x32_bf16(AH, BH, ACC, 0, 0, 0);      \
    ACC = __builtin_amdgcn_mfma_f32_16x16x32_bf16(AH, BL, ACC, 0, 0, 0);      \
    ACC = __builtin_amdgcn_mfma_f32_16x16x32_bf16(AL, BH, ACC, 0, 0, 0);

#define RDA(BP, IB)                                                           \
    _Pragma("unroll")                                                         \
    for (int i = 0; i < 4; ++i) {                                             \
        a_h[i] = *(const v8s*)((BP) + abA + ((IB) + i) * 512);                \
        a_l[i] = *(const v8s*)((BP) + abA + 8192 + ((IB) + i) * 512);         \
    }

#define RDB(BP, JB)                                                           \
    _Pragma("unroll")                                                         \
    for (int j = 0; j < 2; ++j) {                                             \
        b_h[j] = *(const v8s*)((BP) + abB + ((JB) + j) * 512);                \
        b_l[j] = *(const v8s*)((BP) + abB + 8192 + ((JB) + j) * 512);         \
    }

#define PHASE(IB, JB)                                                         \
    LGW();                                                                    \
    __builtin_amdgcn_sched_barrier(0);                                        \
    __builtin_amdgcn_s_setprio(1);                                            \
    _Pragma("unroll")                                                         \
    for (int j = 0; j < 2; ++j) {                                             \
        _Pragma("unroll")                                                     \
        for (int i = 0; i < 4; ++i) {                                         \
            MFMA3(a_h[i], a_l[i], b_h[j], b_l[j], acc[(IB) + i][(JB) + j]);   \
        }                                                                     \
    }                                                                         \
    __builtin_amdgcn_s_setprio(0);

template <int OM, bool BNR>
__global__ __launch_bounds__(512, 2)
void conv3g(Tab3 T,
            const ush* __restrict__ Wh, const ush* __restrict__ Wl,
            const float* __restrict__ bng, const float* __restrict__ bnb,
            const float* __restrict__ bnm, const float* __restrict__ bnv)
{
    constexpr int K = 2304, KC = 72;
    constexpr int BUFS = 32768;   // shorts per buffer (64KB)

    // bijective XCD-aware swizzle on the 1-D grid
    const int nwg = gridDim.x;
    const int flat = blockIdx.x;
    const int xcd = flat & 7, sidx = flat >> 3;
    const int q = nwg >> 3, r8 = nwg & 7;
    const int nf = (xcd < r8 ? xcd * (q + 1) : r8 * (q + 1) + (xcd - r8) * q) + sidx;

    // level lookup
    int li = 0;
    if (nf >= T.l[1].bstart) li = 1;
    if (nf >= T.l[2].bstart) li = 2;
    if (nf >= T.l[3].bstart) li = 3;
    const int logS = T.l[li].logS, logHW = T.l[li].logHW;
    const int S = 1 << logS, HW = 1 << logHW, P = S + 2;
    const ush* __restrict__ Xh = T.l[li].xh;
    const ush* __restrict__ Xl = T.l[li].xl;
    ush* __restrict__ Yh = T.l[li].yh;
    ush* __restrict__ Yl = T.l[li].yl;
    const float* __restrict__ bias = T.l[li].bias;
    const int wofs = T.l[li].wofs;
    const int n0 = (nf - T.l[li].bstart) * 256;

    __shared__ __align__(16) short lds[2][BUFS];
    // buffer layout (shorts): Ah 0 | Al 8192 | Bh 16384 | Bl 24576

    const int tid = threadIdx.x;
    const int lane = tid & 63, w = tid >> 6;
    const int wm = w & 1, wn = w >> 1;       // wave tile: 128 co x 64 px
    const int l15 = lane & 15, l4 = lane >> 4;
    const int lr = lane >> 2, ls = lane & 3;
    const int sw = ls ^ ((lr >> 1) & 3);

    const int role = w >> 1, part = w & 1;   // 0:Ah 1:Al 2:Bh 3:Bl
    const ush* gsrc = role == 0 ? Wh + wofs : role == 1 ? Wl + wofs
                    : role == 2 ? Xh : Xl;
    const int poff = role * 8192 + part * 4096;

    int sb[8];
    if (role < 2) {
#pragma unroll
        for (int t = 0; t < 8; ++t)
            sb[t] = (part * 128 + t * 16 + lr) * K + sw * 8;
    } else {
#pragma unroll
        for (int t = 0; t < 8; ++t) {
            const int p = n0 + part * 128 + t * 16 + lr;
            const int bb = p >> logHW, hw = p & (HW - 1);
            const int oh = hw >> logS, ow = hw & (S - 1);
            sb[t] = ((bb * P + oh + 1) * P + ow + 1) * 256 + sw * 8;
        }
    }

    // stage full chunk c into buffer u (8 x 16B DMA per wave, uniform)
    auto stage = [&](int u, int c) {
        short* db = &lds[0][0] + u * BUFS + poff;
        int coff;
        if (role < 2) coff = c * 32;
        else {
            const int rs = c >> 3;             // tap 0..8 (uniform)
            const int rr = (rs * 11) >> 5;     // rs / 3
            const int ss = rs - 3 * rr;
            coff = ((rr - 1) * P + (ss - 1)) * 256 + (c & 7) * 32;
        }
#pragma unroll
        for (int t = 0; t < 8; ++t)
            gl_lds16(gsrc + (sb[t] + coff), db + t * 512);
    };

    // fragment base offsets within a buffer (shorts); per-i/j step = 512
    const int slr = (l4 ^ ((l15 >> 1) & 3)) * 8;
    const int abA = (wm * 128 + l15) * 32 + slr;
    const int abB = 16384 + (wn * 64 + l15) * 32 + slr;

    v4f acc[8][4] = {};
    v8s a_h[4], a_l[4], b_h[2], b_l[2];

    // prologue: chunk 0 staged; wait + barrier
    stage(0, 0);
    VMW(0);
    __builtin_amdgcn_sched_barrier(0);
    __builtin_amdgcn_s_barrier();

    int cur = 0;
    for (int c = 0; c < KC; ++c) {
        if (c + 1 < KC) stage(cur ^ 1, c + 1);
        const short* bp = &lds[0][0] + cur * BUFS;

        RDA(bp, 0); RDB(bp, 0);
        PHASE(0, 0);            // i0-3 x j0-1
        RDA(bp, 4);
        PHASE(4, 0);            // i4-7 x j0-1
        RDB(bp, 2);
        PHASE(4, 2);            // i4-7 x j2-3 (A regs still i4-7)
        RDA(bp, 0);
        PHASE(0, 2);            // i0-3 x j2-3

        if (c + 1 < KC) VMW(0); // drains DMA issued at top of THIS chunk
        __builtin_amdgcn_sched_barrier(0);
        __builtin_amdgcn_s_barrier();
        cur ^= 1;
    }

    // ---- epilogue: col = lane&15 (pixel), row = (lane>>4)*4+e (co) ----
#pragma unroll
    for (int i = 0; i < 8; ++i) {
        const int co = wm * 128 + i * 16 + l4 * 4;
        float sc[4], sh[4];
#pragma unroll
        for (int e = 0; e < 4; ++e) {
            if (BNR) {
                const float inv = bng[co + e] * rsqrtf(bnv[co + e] + 1e-5f);
                sc[e] = inv;
                sh[e] = (bias[co + e] - bnm[co + e]) * inv + bnb[co + e];
            } else { sc[e] = 1.f; sh[e] = bias[co + e]; }
        }
#pragma unroll
        for (int j = 0; j < 4; ++j) {
            const int ncol = n0 + wn * 64 + j * 16 + l15;
            const int b  = ncol >> logHW;
            const int hw = ncol & (HW - 1);
            float val[4];
#pragma unroll
            for (int e = 0; e < 4; ++e) {
                float x = acc[i][j][e] * sc[e] + sh[e];
                if (BNR) x = fmaxf(x, 0.f);
                val[e] = x;
            }
            int pidx;
            if (OM == 0) {
                const int oh = hw >> logS, ow = hw & (S - 1);
                pidx = (b * P + oh + 1) * P + ow + 1;
            } else {
                pidx = ncol;
            }
            const int addr = pidx * 256 + co;
            ush hs[4], ls2[4];
#pragma unroll
            for (int e = 0; e < 4; ++e) splitf(val[e], hs[e], ls2[e]);
            *(uint2*)&Yh[addr] = make_uint2(hs[0] | ((unsigned)hs[1] << 16),
                                            hs[2] | ((unsigned)hs[3] << 16));
            *(uint2*)&Yl[addr] = make_uint2(ls2[0] | ((unsigned)ls2[1] << 16),
                                            ls2[2] | ((unsigned)ls2[3] << 16));
        }
    }
}

// ---------------------------------------------------------------------------
// Fused scatter head-conv2 (1x1, K=256, Cout=9*DD, fp32 scatter epilogue).
// 4 waves, 128 px/block, co0 = 0 (Cout <= 128; weights zero-padded to 128).
// ---------------------------------------------------------------------------
template <int DD>
__global__ __launch_bounds__(256, 3)
void conv_sf(TabS T, const ush* __restrict__ Wh, const ush* __restrict__ Wl,
             const float* __restrict__ bias, float* __restrict__ out)
{
    constexpr int K = 256, KC = 8, Cout = 9 * DD;
    constexpr int coloff = (DD == 10) ? 4 : 0;

    const int nwg = gridDim.x;
    const int flat = blockIdx.x;
    const int xcd = flat & 7, sidx = flat >> 3;
    const int q = nwg >> 3, r8 = nwg & 7;
    const int nf = (xcd < r8 ? xcd * (q + 1) : r8 * (q + 1) + (xcd - r8) * q) + sidx;

    int li = 0;
    if (nf >= T.l[1].bstart) li = 1;
    if (nf >= T.l[2].bstart) li = 2;
    if (nf >= T.l[3].bstart) li = 3;
    const int logHW = T.l[li].logHW;
    const int HW = 1 << logHW;
    const ush* __restrict__ Xh = T.l[li].xh;
    const ush* __restrict__ Xl = T.l[li].xl;
    const int abase = T.l[li].abase, ibase = T.l[li].ibase;
    const int n0 = (nf - T.l[li].bstart) * 128;

    __shared__ short lds[4][128][32];

    const int tid = threadIdx.x;
    const int lane = tid & 63;
    const int w = tid >> 6;
    const int wm = w & 1, wn = w >> 1;
    const int l15 = lane & 15, l4 = lane >> 4;
    const int lr = lane >> 2, ls = lane & 3;
    const int sw = ls ^ ((lr >> 1) & 3);
    const ush* gsrc = (w == 0) ? Wh : (w == 1) ? Wl : (w == 2) ? Xh : Xl;
    int sb[8];
    if (w < 2) {
#pragma unroll
        for (int t = 0; t < 8; ++t)
            sb[t] = (t * 16 + lr) * K + sw * 8;
    } else {
#pragma unroll
        for (int t = 0; t < 8; ++t)
            sb[t] = (n0 + t * 16 + lr) * 256 + sw * 8;
    }
    short* mypl = &lds[w][0][0];
    const int slA = (l4 ^ ((l15 >> 1) & 3)) * 8;

    v4f acc[4][4] = {};

    for (int c = 0; c < KC; ++c) {
        const int coff = c * 32;
#pragma unroll
        for (int t = 0; t < 8; ++t)
            gl_lds16(gsrc + (sb[t] + coff), mypl + t * 512);

        __syncthreads();

        v8s ah[4], al[4];
#pragma unroll
        for (int i = 0; i < 4; ++i) {
            ah[i] = *(const v8s*)&lds[0][wm * 64 + i * 16 + l15][slA];
            al[i] = *(const v8s*)&lds[1][wm * 64 + i * 16 + l15][slA];
        }
#pragma unroll
        for (int j = 0; j < 4; ++j) {
            const v8s bh = *(const v8s*)&lds[2][wn * 64 + j * 16 + l15][slA];
            const v8s bl = *(const v8s*)&lds[3][wn * 64 + j * 16 + l15][slA];
#pragma unroll
            for (int i = 0; i < 4; ++i) {
                acc[i][j] = __builtin_amdgcn_mfma_f32_16x16x32_bf16(ah[i], bh, acc[i][j], 0, 0, 0);
                acc[i][j] = __builtin_amdgcn_mfma_f32_16x16x32_bf16(ah[i], bl, acc[i][j], 0, 0, 0);
                acc[i][j] = __builtin_amdgcn_mfma_f32_16x16x32_bf16(al[i], bh, acc[i][j], 0, 0, 0);
            }
        }
        __syncthreads();
    }

#pragma unroll
    for (int i = 0; i < 4; ++i) {
        const int co = wm * 64 + i * 16 + l4 * 4;
        float sh[4];
#pragma unroll
        for (int e = 0; e < 4; ++e)
            sh[e] = (co + e < Cout) ? bias[co + e] : 0.f;
#pragma unroll
        for (int j = 0; j < 4; ++j) {
            const int ncol = n0 + wn * 64 + j * 16 + l15;
            const int b  = ncol >> logHW;
            const int hw = ncol & (HW - 1);
#pragma unroll
            for (int e = 0; e < 4; ++e) {
                const int c2 = co + e;
                if (c2 < Cout) {
                    const float val = acc[i][j][e] + sh[e];
                    const int a = c2 / DD, cl = c2 - a * DD;
                    out[(size_t)((b + ibase) * TOTAL_ANCH + abase + hw * 9 + a) * 14
                        + coloff + cl] = val;
                }
            }
        }
    }
}

// ---------------------------------------------------------------------------
// R1 128^2 kernel — retained for the 1x1 lateral convs (KS=1, OM=0).
// ---------------------------------------------------------------------------
template <int KS, int OM, bool BNR, int DD>
__global__ __launch_bounds__(256, 3)
void conv_mfma(const ush* __restrict__ Xh, const ush* __restrict__ Xl,
               const ush* __restrict__ Wh, const ush* __restrict__ Wl,
               const float* __restrict__ bias,
               ush* __restrict__ Yh, ush* __restrict__ Yl,
               int K, int logS, int logHW, int Kin)
{
    const int tid = threadIdx.x;

    const int nwg  = gridDim.x * gridDim.y;
    const int flat = blockIdx.y * gridDim.x + blockIdx.x;
    const int xcd = flat & 7, sidx = flat >> 3;
    const int q = nwg >> 3, r8 = nwg & 7;
    const int nf = (xcd < r8 ? xcd * (q + 1) : r8 * (q + 1) + (xcd - r8) * q) + sidx;
    int bx, by;
    if (gridDim.y == 2) { bx = nf >> 1; by = nf & 1; }
    else                { bx = nf;      by = 0;      }

    const int n0  = bx * 128;
    const int co0 = by * 128;
    const int S = 1 << logS, HW = 1 << logHW, P = S + 2;

    __shared__ short lds[4][128][32];

    const int lane = tid & 63;
    const int w = tid >> 6;
    const int wm = w & 1, wn = w >> 1;
    const int l15 = lane & 15, l4 = lane >> 4;

    const int lr = lane >> 2, ls = lane & 3;
    const int sw = ls ^ ((lr >> 1) & 3);
    const ush* gsrc = (w == 0) ? Wh : (w == 1) ? Wl : (w == 2) ? Xh : Xl;
    int sb[8];
    if (w < 2) {
#pragma unroll
        for (int t = 0; t < 8; ++t)
            sb[t] = (co0 + t * 16 + lr) * K + sw * 8;
    } else {
#pragma unroll
        for (int t = 0; t < 8; ++t) {
            const int p = n0 + t * 16 + lr;
            sb[t] = p * Kin + sw * 8;
        }
    }
    short* mypl = &lds[w][0][0];

    const int KC = K >> 5;
    const int slA = (l4 ^ ((l15 >> 1) & 3)) * 8;

    v4f acc[4][4] = {};

    for (int c = 0; c < KC; ++c) {
        const int coff = c * 32;
#pragma unroll
        for (int t = 0; t < 8; ++t)
            gl_lds16(gsrc + (sb[t] + coff), mypl + t * 512);

        __syncthreads();

        v8s ah[4], al[4];
#pragma unroll
        for (int i = 0; i < 4; ++i) {
            ah[i] = *(const v8s*)&lds[0][wm * 64 + i * 16 + l15][slA];
            al[i] = *(const v8s*)&lds[1][wm * 64 + i * 16 + l15][slA];
        }
#pragma unroll
        for (int j = 0; j < 4; ++j) {
            const v8s bh = *(const v8s*)&lds[2][wn * 64 + j * 16 + l15][slA];
            const v8s bl = *(const v8s*)&lds[3][wn * 64 + j * 16 + l15][slA];
#pragma unroll
            for (int i = 0; i < 4; ++i) {
                acc[i][j] = __builtin_amdgcn_mfma_f32_16x16x32_bf16(ah[i], bh, acc[i][j], 0, 0, 0);
                acc[i][j] = __builtin_amdgcn_mfma_f32_16x16x32_bf16(ah[i], bl, acc[i][j], 0, 0, 0);
                acc[i][j] = __builtin_amdgcn_mfma_f32_16x16x32_bf16(al[i], bh, acc[i][j], 0, 0, 0);
            }
        }
        __syncthreads();
    }

#pragma unroll
    for (int i = 0; i < 4; ++i) {
        const int cob = wm * 64 + i * 16 + l4 * 4;
        const int co  = co0 + cob;
        float sh[4];
#pragma unroll
        for (int e = 0; e < 4; ++e) sh[e] = bias[co + e];
#pragma unroll
        for (int j = 0; j < 4; ++j) {
            const int ncol = n0 + wn * 64 + j * 16 + l15;
            const int b  = ncol >> logHW;
            const int hw = ncol & (HW - 1);
            float val[4];
#pragma unroll
            for (int e = 0; e < 4; ++e) val[e] = acc[i][j][e] + sh[e];
            int pidx;
            if (OM == 0) {
                const int oh = hw >> logS, ow = hw & (S - 1);
                pidx = (b * P + oh + 1) * P + ow + 1;
            } else {
                pidx = ncol;
            }
            const int addr = pidx * 256 + co;
            ush hs[4], ls2[4];
#pragma unroll
            for (int e = 0; e < 4; ++e) splitf(val[e], hs[e], ls2[e]);
            *(uint2*)&Yh[addr] = make_uint2(hs[0] | ((unsigned)hs[1] << 16),
                                            hs[2] | ((unsigned)hs[3] << 16));
            *(uint2*)&Yl[addr] = make_uint2(ls2[0] | ((unsigned)ls2[1] << 16),
                                            ls2[2] | ((unsigned)ls2[3] << 16));
        }
    }
}

// ---- prep / glue kernels -------------------------------------------------

__global__ void w3_prep(const float* __restrict__ W, ush* __restrict__ wh,
                        ush* __restrict__ wl, int total) {
    const int idx = blockIdx.x * 256 + threadIdx.x;
    if (idx >= total) return;
    const int co5 = idx / 2304;
    const int kk  = idx - co5 * 2304;
    const int rs = kk >> 8, ci = kk & 255;
    splitf(W[(co5 * 256 + ci) * 9 + rs], wh[idx], wl[idx]);
}

__global__ void w1_prep(const float* __restrict__ W, ush* __restrict__ wh,
                        ush* __restrict__ wl, int Cin, int Kp, int Cout, int total) {
    const int idx = blockIdx.x * 256 + threadIdx.x;
    if (idx >= total) return;
    const int co = idx / Kp;
    const int k  = idx - co * Kp;
    const float x = (co < Cout && k < Cin) ? W[co * Cin + k] : 0.f;
    splitf(x, wh[idx], wl[idx]);
}

__global__ void in_prep(const float* __restrict__ f, ush* __restrict__ xh,
                        ush* __restrict__ xl, int Cin, int Kp, int logHW, int total) {
    const int idx = blockIdx.x * 256 + threadIdx.x;
    if (idx >= total) return;
    const int c = idx % Kp;
    const int n = idx / Kp;
    const int b  = n >> logHW;
    const int hw = n & ((1 << logHW) - 1);
    const float x = (c < Cin) ? f[((b * Cin + c) << logHW) + hw] : 0.f;
    splitf(x, xh[idx], xl[idx]);
}

__global__ void upsample_hl(ush* __restrict__ fh, ush* __restrict__ fl,
                            const ush* __restrict__ ch, const ush* __restrict__ cl2,
                            int logSf, int total) {
    const int idx = blockIdx.x * 256 + threadIdx.x;
    if (idx >= total) return;
    const int ci = idx & 255;
    const int r  = idx >> 8;
    const int Sf = 1 << logSf;
    const int wf = r & (Sf - 1);
    const int hf = (r >> logSf) & (Sf - 1);
    const int b  = r >> (2 * logSf);
    const int Pf = Sf + 2, Pc = (Sf >> 1) + 2;
    const int fi = ((b * Pf + hf + 1) * Pf + wf + 1) * 256 + ci;
    const int cx = ((b * Pc + (hf >> 1) + 1) * Pc + (wf >> 1) + 1) * 256 + ci;
    const float x = bf2f(fh[fi]) + bf2f(fl[fi]) + bf2f(ch[cx]) + bf2f(cl2[cx]);
    splitf(x, fh[fi], fl[fi]);
}

__global__ void ring_zero(ush* __restrict__ yh, ush* __restrict__ yl, int S, int total) {
    const int idx = blockIdx.x * 256 + threadIdx.x;
    if (idx >= total) return;
    const int ci = idx & 255;
    const int r  = idx >> 8;
    const int P = S + 2;
    const int ring = 4 * P - 4;
    const int pr = r % ring;
    const int b  = r / ring;
    int ph, pw;
    if (pr < P)            { ph = 0;     pw = pr; }
    else if (pr < 2 * P)   { ph = P - 1; pw = pr - P; }
    else { const int q = pr - 2 * P; ph = 1 + (q >> 1); pw = (q & 1) ? (P - 1) : 0; }
    const int a = ((b * P + ph) * P + pw) * 256 + ci;
    yh[a] = 0; yl[a] = 0;
}

// ---------------------------------------------------------------------------

extern "C" void kernel_launch(void* const* d_in, const int* in_sizes, int n_in,
                              void* d_out, int out_size, void* d_ws, size_t ws_size,
                              hipStream_t stream)
{
    const float* f[5];     const float* lat_w[5];
    for (int i = 0; i < 5; ++i) f[i] = (const float*)d_in[i];
    for (int i = 0; i < 5; ++i) lat_w[i] = (const float*)d_in[5 + i];
    const float* lat_b  = (const float*)d_in[10];
    const float* fpn_w  = (const float*)d_in[11];
    const float* fpn_b  = (const float*)d_in[12];
    const float* cls_w1 = (const float*)d_in[13];
    const float* cls_b1 = (const float*)d_in[14];
    const float* cls_g  = (const float*)d_in[15];
    const float* cls_bt = (const float*)d_in[16];
    const float* cls_m  = (const float*)d_in[17];
    const float* cls_v  = (const float*)d_in[18];
    const float* cls_w2 = (const float*)d_in[19];
    const float* cls_b2 = (const float*)d_in[20];
    const float* reg_w1 = (const float*)d_in[21];
    const float* reg_b1 = (const float*)d_in[22];
    const float* reg_g  = (const float*)d_in[23];
    const float* reg_bt = (const float*)d_in[24];
    const float* reg_m  = (const float*)d_in[25];
    const float* reg_v  = (const float*)d_in[26];
    const float* reg_w2 = (const float*)d_in[27];
    const float* reg_b2 = (const float*)d_in[28];

    float* out = (float*)d_out;
    ush*   ws16 = (ush*)d_ws;

    static const int S_[5]     = {128, 64, 32, 16, 8};
    static const int logS_[5]  = {7, 6, 5, 4, 3};
    static const int logHW_[5] = {14, 12, 10, 8, 6};
    static const int HW_[5]    = {16384, 4096, 1024, 256, 64};
    static const int Cin_[5]   = {32, 48, 96, 136, 232};
    static const int Kp_[5]    = {32, 64, 96, 160, 256};
    static const int abase_[5] = {0, 147456, 184320, 193536, 195840};
    constexpr int BIG = 0x7fffffff;

    size_t off = 0;
    auto alloc = [&](size_t elems) {
        ush* p = ws16 + off;
        off += (elems + 63) & ~(size_t)63;
        return p;
    };

    // --- persistent: padded lateral planes (reused as head-conv1 tmp) ---
    ush *lat_h[5], *lat_l[5];
    for (int i = 0; i < 5; ++i) {
        const int P = S_[i] + 2;
        const size_t e = (size_t)2048 * P * P;   // 8 images * P*P * 256
        lat_h[i] = alloc(e); lat_l[i] = alloc(e);
    }
    const size_t lat_bytes = off * sizeof(ush);

    // --- shared transient arena (69.2 MB) ---
    const size_t ARENA_E = (size_t)2 * 4 * 130 * 130 * 256;
    ush* arena = alloc(ARENA_E);

    // --- weights (head conv2 padded to 128 co-rows for unguarded DMA) ---
    ush* fw_h = alloc((size_t)5 * 256 * 2304); ush* fw_l = alloc((size_t)5 * 256 * 2304);
    ush* cw_h = alloc(256 * 2304);             ush* cw_l = alloc(256 * 2304);
    ush* rw_h = alloc(256 * 2304);             ush* rw_l = alloc(256 * 2304);
    ush *lw_h[5], *lw_l[5];
    for (int i = 0; i < 5; ++i) { lw_h[i] = alloc(256 * Kp_[i]); lw_l[i] = alloc(256 * Kp_[i]); }
    ush* c2_h = alloc(128 * 256); ush* c2_l = alloc(128 * 256);
    ush* r2_h = alloc(128 * 256); ush* r2_l = alloc(128 * 256);

    hipMemsetAsync(ws16, 0, lat_bytes, stream);

    // --- weight prep ---
    {
        int t = 5 * 256 * 2304;
        w3_prep<<<dim3((t + 255) / 256), 256, 0, stream>>>(fpn_w, fw_h, fw_l, t);
        t = 256 * 2304;
        w3_prep<<<dim3((t + 255) / 256), 256, 0, stream>>>(cls_w1, cw_h, cw_l, t);
        w3_prep<<<dim3((t + 255) / 256), 256, 0, stream>>>(reg_w1, rw_h, rw_l, t);
        for (int i = 0; i < 5; ++i) {
            t = 256 * Kp_[i];
            w1_prep<<<dim3((t + 255) / 256), 256, 0, stream>>>(lat_w[i], lw_h[i], lw_l[i], Cin_[i], Kp_[i], 256, t);
        }
        t = 128 * 256;
        w1_prep<<<dim3((t + 255) / 256), 256, 0, stream>>>(cls_w2, c2_h, c2_l, 256, 256, 90, t);
        w1_prep<<<dim3((t + 255) / 256), 256, 0, stream>>>(reg_w2, r2_h, r2_l, 256, 256, 36, t);
    }

    // --- input conversion + lateral 1x1 convs (arena transient) ---
    for (int i = 0; i < 5; ++i) {
        const int N = 8 * HW_[i];
        const int t = N * Kp_[i];
        ush* xh = arena;
        ush* xl = arena + (size_t)N * Kp_[i];
        in_prep<<<dim3((t + 255) / 256), 256, 0, stream>>>(f[i], xh, xl, Cin_[i], Kp_[i], logHW_[i], t);
        conv_mfma<1, 0, false, 0><<<dim3(N / 128, 2), 256, 0, stream>>>(
            xh, xl, lw_h[i], lw_l[i], lat_b + i * 256,
            lat_h[i], lat_l[i],
            Kp_[i], logS_[i], logHW_[i], Kp_[i]);
    }

    // --- top-down pathway ---
    for (int i = 4; i >= 1; --i) {
        const int t = 8 * HW_[i - 1] * 256;
        upsample_hl<<<dim3((t + 255) / 256), 256, 0, stream>>>(
            lat_h[i - 1], lat_l[i - 1], lat_h[i], lat_l[i], logS_[i - 1], t);
    }

    // --- levels 1..4 FUSED: all 4 fpn plane pairs resident in arena ---
    ush *fpn_h4[5], *fpn_l4[5];
    {
        size_t o = 0;
        for (int i = 1; i < 5; ++i) {
            const int P = S_[i] + 2;
            fpn_h4[i] = arena + o; o += (size_t)2048 * P * P;
            fpn_l4[i] = arena + o; o += (size_t)2048 * P * P;
        }
    }
    for (int i = 1; i < 5; ++i) {
        const int P = S_[i] + 2;
        const int rt = 8 * (4 * P - 4) * 256;
        ring_zero<<<dim3((rt + 255) / 256), 256, 0, stream>>>(fpn_h4[i], fpn_l4[i], S_[i], rt);
    }
    static const int bstart4[4] = {0, 128, 160, 168};   // 128+32+8+2 = 170 (256px blocks)
    static const int bstartS[4] = {0, 256, 320, 336};   // 340 (128px blocks, conv_sf)

    {   // fused fpn conv (per-level weight slice + bias)
        Tab3 T{};
        for (int k = 0; k < 4; ++k) {
            const int i = k + 1;
            T.l[k] = Lvl3{ lat_h[i], lat_l[i], fpn_h4[i], fpn_l4[i],
                           fpn_b + i * 256, i * 256 * 2304,
                           logS_[i], logHW_[i], bstart4[k] };
        }
        conv3g<0, false><<<dim3(170), 512, 0, stream>>>(
            T, fw_h, fw_l, nullptr, nullptr, nullptr, nullptr);
    }
    {   // fused cls conv1 -> tmp (lat planes)
        Tab3 T{};
        for (int k = 0; k < 4; ++k) {
            const int i = k + 1;
            T.l[k] = Lvl3{ fpn_h4[i], fpn_l4[i], lat_h[i], lat_l[i],
                           cls_b1, 0, logS_[i], logHW_[i], bstart4[k] };
        }
        conv3g<1, true><<<dim3(170), 512, 0, stream>>>(
            T, cw_h, cw_l, cls_g, cls_bt, cls_m, cls_v);
    }
    {   // fused cls conv2 scatter
        TabS T{};
        for (int k = 0; k < 4; ++k) {
            const int i = k + 1;
            T.l[k] = LvlS{ lat_h[i], lat_l[i], abase_[i], logHW_[i], bstartS[k], 0 };
        }
        conv_sf<10><<<dim3(340), 256, 0, stream>>>(T, c2_h, c2_l, cls_b2, out);
    }
    {   // fused reg conv1 -> tmp
        Tab3 T{};
        for (int k = 0; k < 4; ++k) {
            const int i = k + 1;
            T.l[k] = Lvl3{ fpn_h4[i], fpn_l4[i], lat_h[i], lat_l[i],
                           reg_b1, 0, logS_[i], logHW_[i], bstart4[k] };
        }
        conv3g<1, true><<<dim3(170), 512, 0, stream>>>(
            T, rw_h, rw_l, reg_g, reg_bt, reg_m, reg_v);
    }
    {   // fused reg conv2 scatter
        TabS T{};
        for (int k = 0; k < 4; ++k) {
            const int i = k + 1;
            T.l[k] = LvlS{ lat_h[i], lat_l[i], abase_[i], logHW_[i], bstartS[k], 0 };
        }
        conv_sf<4><<<dim3(340), 256, 0, stream>>>(T, r2_h, r2_l, reg_b2, out);
    }

    // --- level 0: two 4-image groups (1-entry tables; 256 blocks = 1 round) ---
    {
        const int P = 130;
        const size_t padg = (size_t)4 * P * P * 256;     // padded, 4 images
        const size_t unpg = (size_t)4 * 16384 * 256;     // unpadded, 4 images
        for (int g = 0; g < 2; ++g) {
            ush* fpn_h = arena;
            ush* fpn_l = arena + padg;
            ush* lat0p_h = lat_h[0] + (size_t)g * padg;
            ush* lat0p_l = lat_l[0] + (size_t)g * padg;
            ush* tmp_h   = lat_h[0] + (size_t)g * unpg;
            ush* tmp_l   = lat_l[0] + (size_t)g * unpg;
            const int rt = 4 * (4 * P - 4) * 256;
            ring_zero<<<dim3((rt + 255) / 256), 256, 0, stream>>>(fpn_h, fpn_l, 128, rt);

            Tab3 T{};
            T.l[0] = Lvl3{ lat0p_h, lat0p_l, fpn_h, fpn_l, fpn_b, 0, 7, 14, 0 };
            for (int k = 1; k < 4; ++k) T.l[k].bstart = BIG;
            conv3g<0, false><<<dim3(256), 512, 0, stream>>>(
                T, fw_h, fw_l, nullptr, nullptr, nullptr, nullptr);

            Tab3 Tc{};
            Tc.l[0] = Lvl3{ fpn_h, fpn_l, tmp_h, tmp_l, cls_b1, 0, 7, 14, 0 };
            for (int k = 1; k < 4; ++k) Tc.l[k].bstart = BIG;
            conv3g<1, true><<<dim3(256), 512, 0, stream>>>(
                Tc, cw_h, cw_l, cls_g, cls_bt, cls_m, cls_v);

            TabS Ts{};
            Ts.l[0] = LvlS{ tmp_h, tmp_l, 0, 14, 0, 4 * g };
            for (int k = 1; k < 4; ++k) Ts.l[k].bstart = BIG;
            conv_sf<10><<<dim3(512), 256, 0, stream>>>(Ts, c2_h, c2_l, cls_b2, out);

            Tab3 Tr{};
            Tr.l[0] = Lvl3{ fpn_h, fpn_l, tmp_h, tmp_l, reg_b1, 0, 7, 14, 0 };
            for (int k = 1; k < 4; ++k) Tr.l[k].bstart = BIG;
            conv3g<1, true><<<dim3(256), 512, 0, stream>>>(
                Tr, rw_h, rw_l, reg_g, reg_bt, reg_m, reg_v);

            TabS Tq{};
            Tq.l[0] = LvlS{ tmp_h, tmp_l, 0, 14, 0, 4 * g };
            for (int k = 1; k < 4; ++k) Tq.l[k].bstart = BIG;
            conv_sf<4><<<dim3(512), 256, 0, stream>>>(Tq, r2_h, r2_l, reg_b2, out);
        }
    }
}

// Round 6
// 2382.498 us; speedup vs baseline: 1.4887x; 1.0058x over previous
//
#include <hip/hip_runtime.h>

// ---------------------------------------------------------------------------
// EfficientDet head on MFMA (gfx950), split-bf16 (hi+lo) fp32-accurate GEMM.
// All convs = implicit GEMM: C[co][n] = W[co][k] * Im2col[k][n].
// Activations: NHWC bf16 hi/lo planes; 3x3 inputs spatially zero-padded P=S+2.
// K order for 3x3: k = (r*3+s)*256 + ci  (tap-major -> contiguous ci chunks).
// 3 MFMAs per tile-pair: AhiBhi + AhiBlo + AloBhi  (error ~2^-17 relative).
//
// R6: conv3g inner chunk restructured as a counted-lgkmcnt j-pipeline:
//   read all 8 A-pairs once (16 ds_read_b128) + B0 + B1; lgkmcnt(2) -> MFMA
//   j0 while B1 in flight; issue B2; lgkmcnt(2) -> MFMA j1; issue B3;
//   lgkmcnt(2) -> MFMA j2; lgkmcnt(0) -> MFMA j3. Each ds_read batch's
//   latency hides under the previous 24-MFMA cluster; A re-read eliminated
//   (24 vs 32 pair-reads/wave/chunk). Dual B register sets (bX/bY, static
//   names per rule #20); sched_barrier(0) after each wait (rule #18).
//   Chunk boundary: vmcnt(0) drains DMA issued a full chunk earlier + one
//   barrier (double-buffered 2x64KB LDS, 256co x 256px block, 8 waves).
// 1x1 lateral + head-scatter convs keep the R1 128^2 global_load_lds kernel.
// ---------------------------------------------------------------------------

typedef unsigned short ush;
typedef __attribute__((ext_vector_type(8))) short v8s;
typedef __attribute__((ext_vector_type(4))) float v4f;

constexpr int TOTAL_ANCH = 196416;  // 9 * (128^2+64^2+32^2+16^2+8^2)

#define VMW(n) asm volatile("s_waitcnt vmcnt(" #n ")" ::: "memory")
#define LGK(n) asm volatile("s_waitcnt lgkmcnt(" #n ")" ::: "memory")
#define SB0()  __builtin_amdgcn_sched_barrier(0)

__device__ __forceinline__ ush f2bf(float x) {
    unsigned u = __builtin_bit_cast(unsigned, x);
    u += 0x7FFFu + ((u >> 16) & 1u);
    return (ush)(u >> 16);
}
__device__ __forceinline__ float bf2f(ush h) {
    unsigned u = ((unsigned)h) << 16;
    return __builtin_bit_cast(float, u);
}
__device__ __forceinline__ void splitf(float x, ush& hi, ush& lo) {
    hi = f2bf(x);
    lo = f2bf(x - bf2f(hi));
}

__device__ __forceinline__ void gl_lds16(const ush* g, short* l) {
    __builtin_amdgcn_global_load_lds(
        (const __attribute__((address_space(1))) unsigned*)(const void*)g,
        (__attribute__((address_space(3))) unsigned*)l, 16, 0, 0);
}

// per-level work descriptors (kernel args by value)
struct Lvl3 {
    const ush* xh; const ush* xl;    // input planes (padded NHWC hi/lo)
    ush* yh; ush* yl;                // output planes
    const float* bias;
    int wofs, logS, logHW, bstart;   // weight elem offset; block range start
};
struct Tab3 { Lvl3 l[4]; };

struct LvlS {
    const ush* xh; const ush* xl;    // input planes (unpadded NHWC hi/lo)
    int abase, logHW, bstart, ibase;
};
struct TabS { LvlS l[4]; };

// ---------------------------------------------------------------------------
// conv3g: deep 3x3 conv, fused multi-level. K=2304, Cout=256, 256 px/block.
// 8 waves: wm=w&1 (co half, 128 rows), wn=w>>1 (px quarter, 64 cols).
// LDS buffer (64KB): Ah[256][32] | Al | Bh[256][32] | Bl (8192 shorts each).
// Staging: role=w>>1 (0:Ah 1:Al 2:Bh 3:Bl), part=w&1 (128-row half); every
// wave 8 x gl_lds16 per chunk. Slot swizzle (both sides, proven 0-conflict):
// seg(row,slot) = slot ^ ((row>>1)&3).
// OM: 0 = padded NHWC hi/lo out; 1 = unpadded NHWC hi/lo out.  BNR: BN+ReLU.
// ---------------------------------------------------------------------------
#define MFMA3(AH, AL, BH, BL, ACC)                                            \
    ACC = __builtin_amdgcn_mfma_f32_16x16x32_bf16(AH, BH, ACC, 0, 0, 0);      \
    ACC = __builtin_amdgcn_mfma_f32_16x16x32_bf16(AH, BL, ACC, 0, 0, 0);      \
    ACC = __builtin_amdgcn_mfma_f32_16x16x32_bf16(AL, BH, ACC, 0, 0, 0);

#define MFMAJ(J, BH, BL)                                                      \
    __builtin_amdgcn_s_setprio(1);                                            \
    _Pragma("unroll")                                                         \
    for (int i = 0; i < 8; ++i) {                                             \
        MFMA3(a_h[i], a_l[i], BH, BL, acc[i][J]);                             \
    }                                                                         \
    __builtin_amdgcn_s_setprio(0);

template <int OM, bool BNR>
__global__ __launch_bounds__(512, 2)
void conv3g(Tab3 T,
            const ush* __restrict__ Wh, const ush* __restrict__ Wl,
            const float* __restrict__ bng, const float* __restrict__ bnb,
            const float* __restrict__ bnm, const float* __restrict__ bnv)
{
    constexpr int K = 2304, KC = 72;
    constexpr int BUFS = 32768;   // shorts per buffer (64KB)

    // bijective XCD-aware swizzle on the 1-D grid
    const int nwg = gridDim.x;
    const int flat = blockIdx.x;
    const int xcd = flat & 7, sidx = flat >> 3;
    const int q = nwg >> 3, r8 = nwg & 7;
    const int nf = (xcd < r8 ? xcd * (q + 1) : r8 * (q + 1) + (xcd - r8) * q) + sidx;

    // level lookup
    int li = 0;
    if (nf >= T.l[1].bstart) li = 1;
    if (nf >= T.l[2].bstart) li = 2;
    if (nf >= T.l[3].bstart) li = 3;
    const int logS = T.l[li].logS, logHW = T.l[li].logHW;
    const int S = 1 << logS, HW = 1 << logHW, P = S + 2;
    const ush* __restrict__ Xh = T.l[li].xh;
    const ush* __restrict__ Xl = T.l[li].xl;
    ush* __restrict__ Yh = T.l[li].yh;
    ush* __restrict__ Yl = T.l[li].yl;
    const float* __restrict__ bias = T.l[li].bias;
    const int wofs = T.l[li].wofs;
    const int n0 = (nf - T.l[li].bstart) * 256;

    __shared__ __align__(16) short lds[2][BUFS];
    // buffer layout (shorts): Ah 0 | Al 8192 | Bh 16384 | Bl 24576

    const int tid = threadIdx.x;
    const int lane = tid & 63, w = tid >> 6;
    const int wm = w & 1, wn = w >> 1;       // wave tile: 128 co x 64 px
    const int l15 = lane & 15, l4 = lane >> 4;
    const int lr = lane >> 2, ls = lane & 3;
    const int sw = ls ^ ((lr >> 1) & 3);

    const int role = w >> 1, part = w & 1;   // 0:Ah 1:Al 2:Bh 3:Bl
    const ush* gsrc = role == 0 ? Wh + wofs : role == 1 ? Wl + wofs
                    : role == 2 ? Xh : Xl;
    const int poff = role * 8192 + part * 4096;

    int sb[8];
    if (role < 2) {
#pragma unroll
        for (int t = 0; t < 8; ++t)
            sb[t] = (part * 128 + t * 16 + lr) * K + sw * 8;
    } else {
#pragma unroll
        for (int t = 0; t < 8; ++t) {
            const int p = n0 + part * 128 + t * 16 + lr;
            const int bb = p >> logHW, hw = p & (HW - 1);
            const int oh = hw >> logS, ow = hw & (S - 1);
            sb[t] = ((bb * P + oh + 1) * P + ow + 1) * 256 + sw * 8;
        }
    }

    // stage full chunk c into buffer u (8 x 16B DMA per wave, uniform)
    auto stage = [&](int u, int c) {
        short* db = &lds[0][0] + u * BUFS + poff;
        int coff;
        if (role < 2) coff = c * 32;
        else {
            const int rs = c >> 3;             // tap 0..8 (uniform)
            const int rr = (rs * 11) >> 5;     // rs / 3
            const int ss = rs - 3 * rr;
            coff = ((rr - 1) * P + (ss - 1)) * 256 + (c & 7) * 32;
        }
#pragma unroll
        for (int t = 0; t < 8; ++t)
            gl_lds16(gsrc + (sb[t] + coff), db + t * 512);
    };

    // fragment base offsets within a buffer (shorts); per-i/j step = 512
    const int slr = (l4 ^ ((l15 >> 1) & 3)) * 8;
    const int abA = (wm * 128 + l15) * 32 + slr;
    const int abB = 16384 + (wn * 64 + l15) * 32 + slr;

    v4f acc[8][4] = {};
    v8s a_h[8], a_l[8];
    v8s bXh, bXl, bYh, bYl;

    // prologue: chunk 0 staged; wait + barrier
    stage(0, 0);
    VMW(0);
    SB0();
    __builtin_amdgcn_s_barrier();

    int cur = 0;
    for (int c = 0; c < KC; ++c) {
        const bool pf = (c + 1) < KC;
        if (pf) stage(cur ^ 1, c + 1);
        const short* bp = &lds[0][0] + cur * BUFS;

        // issue all A reads (16) + B0 (2, ->X) + B1 (2, ->Y)
#pragma unroll
        for (int i = 0; i < 8; ++i) {
            a_h[i] = *(const v8s*)(bp + abA + i * 512);
            a_l[i] = *(const v8s*)(bp + abA + 8192 + i * 512);
        }
        bXh = *(const v8s*)(bp + abB);
        bXl = *(const v8s*)(bp + abB + 8192);
        bYh = *(const v8s*)(bp + abB + 512);
        bYl = *(const v8s*)(bp + abB + 8192 + 512);

        LGK(2); SB0();           // A + B0 complete, B1 in flight
        MFMAJ(0, bXh, bXl);

        bXh = *(const v8s*)(bp + abB + 2 * 512);          // B2 -> X
        bXl = *(const v8s*)(bp + abB + 8192 + 2 * 512);
        LGK(2); SB0();           // B1 complete, B2 in flight
        MFMAJ(1, bYh, bYl);

        bYh = *(const v8s*)(bp + abB + 3 * 512);          // B3 -> Y
        bYl = *(const v8s*)(bp + abB + 8192 + 3 * 512);
        LGK(2); SB0();           // B2 complete, B3 in flight
        MFMAJ(2, bXh, bXl);

        LGK(0); SB0();           // B3 complete
        MFMAJ(3, bYh, bYl);

        if (pf) VMW(0);          // drains DMA issued at top of THIS chunk
        SB0();
        __builtin_amdgcn_s_barrier();
        cur ^= 1;
    }

    // ---- epilogue: col = lane&15 (pixel), row = (lane>>4)*4+e (co) ----
#pragma unroll
    for (int i = 0; i < 8; ++i) {
        const int co = wm * 128 + i * 16 + l4 * 4;
        float sc[4], sh[4];
#pragma unroll
        for (int e = 0; e < 4; ++e) {
            if (BNR) {
                const float inv = bng[co + e] * rsqrtf(bnv[co + e] + 1e-5f);
                sc[e] = inv;
                sh[e] = (bias[co + e] - bnm[co + e]) * inv + bnb[co + e];
            } else { sc[e] = 1.f; sh[e] = bias[co + e]; }
        }
#pragma unroll
        for (int j = 0; j < 4; ++j) {
            const int ncol = n0 + wn * 64 + j * 16 + l15;
            const int b  = ncol >> logHW;
            const int hw = ncol & (HW - 1);
            float val[4];
#pragma unroll
            for (int e = 0; e < 4; ++e) {
                float x = acc[i][j][e] * sc[e] + sh[e];
                if (BNR) x = fmaxf(x, 0.f);
                val[e] = x;
            }
            int pidx;
            if (OM == 0) {
                const int oh = hw >> logS, ow = hw & (S - 1);
                pidx = (b * P + oh + 1) * P + ow + 1;
            } else {
                pidx = ncol;
            }
            const int addr = pidx * 256 + co;
            ush hs[4], ls2[4];
#pragma unroll
            for (int e = 0; e < 4; ++e) splitf(val[e], hs[e], ls2[e]);
            *(uint2*)&Yh[addr] = make_uint2(hs[0] | ((unsigned)hs[1] << 16),
                                            hs[2] | ((unsigned)hs[3] << 16));
            *(uint2*)&Yl[addr] = make_uint2(ls2[0] | ((unsigned)ls2[1] << 16),
                                            ls2[2] | ((unsigned)ls2[3] << 16));
        }
    }
}

// ---------------------------------------------------------------------------
// Fused scatter head-conv2 (1x1, K=256, Cout=9*DD, fp32 scatter epilogue).
// 4 waves, 128 px/block, co0 = 0 (Cout <= 128; weights zero-padded to 128).
// ---------------------------------------------------------------------------
template <int DD>
__global__ __launch_bounds__(256, 3)
void conv_sf(TabS T, const ush* __restrict__ Wh, const ush* __restrict__ Wl,
             const float* __restrict__ bias, float* __restrict__ out)
{
    constexpr int K = 256, KC = 8, Cout = 9 * DD;
    constexpr int coloff = (DD == 10) ? 4 : 0;

    const int nwg = gridDim.x;
    const int flat = blockIdx.x;
    const int xcd = flat & 7, sidx = flat >> 3;
    const int q = nwg >> 3, r8 = nwg & 7;
    const int nf = (xcd < r8 ? xcd * (q + 1) : r8 * (q + 1) + (xcd - r8) * q) + sidx;

    int li = 0;
    if (nf >= T.l[1].bstart) li = 1;
    if (nf >= T.l[2].bstart) li = 2;
    if (nf >= T.l[3].bstart) li = 3;
    const int logHW = T.l[li].logHW;
    const int HW = 1 << logHW;
    const ush* __restrict__ Xh = T.l[li].xh;
    const ush* __restrict__ Xl = T.l[li].xl;
    const int abase = T.l[li].abase, ibase = T.l[li].ibase;
    const int n0 = (nf - T.l[li].bstart) * 128;

    __shared__ short lds[4][128][32];

    const int tid = threadIdx.x;
    const int lane = tid & 63;
    const int w = tid >> 6;
    const int wm = w & 1, wn = w >> 1;
    const int l15 = lane & 15, l4 = lane >> 4;
    const int lr = lane >> 2, ls = lane & 3;
    const int sw = ls ^ ((lr >> 1) & 3);
    const ush* gsrc = (w == 0) ? Wh : (w == 1) ? Wl : (w == 2) ? Xh : Xl;
    int sb[8];
    if (w < 2) {
#pragma unroll
        for (int t = 0; t < 8; ++t)
            sb[t] = (t * 16 + lr) * K + sw * 8;
    } else {
#pragma unroll
        for (int t = 0; t < 8; ++t)
            sb[t] = (n0 + t * 16 + lr) * 256 + sw * 8;
    }
    short* mypl = &lds[w][0][0];
    const int slA = (l4 ^ ((l15 >> 1) & 3)) * 8;

    v4f acc[4][4] = {};

    for (int c = 0; c < KC; ++c) {
        const int coff = c * 32;
#pragma unroll
        for (int t = 0; t < 8; ++t)
            gl_lds16(gsrc + (sb[t] + coff), mypl + t * 512);

        __syncthreads();

        v8s ah[4], al[4];
#pragma unroll
        for (int i = 0; i < 4; ++i) {
            ah[i] = *(const v8s*)&lds[0][wm * 64 + i * 16 + l15][slA];
            al[i] = *(const v8s*)&lds[1][wm * 64 + i * 16 + l15][slA];
        }
#pragma unroll
        for (int j = 0; j < 4; ++j) {
            const v8s bh = *(const v8s*)&lds[2][wn * 64 + j * 16 + l15][slA];
            const v8s bl = *(const v8s*)&lds[3][wn * 64 + j * 16 + l15][slA];
#pragma unroll
            for (int i = 0; i < 4; ++i) {
                acc[i][j] = __builtin_amdgcn_mfma_f32_16x16x32_bf16(ah[i], bh, acc[i][j], 0, 0, 0);
                acc[i][j] = __builtin_amdgcn_mfma_f32_16x16x32_bf16(ah[i], bl, acc[i][j], 0, 0, 0);
                acc[i][j] = __builtin_amdgcn_mfma_f32_16x16x32_bf16(al[i], bh, acc[i][j], 0, 0, 0);
            }
        }
        __syncthreads();
    }

#pragma unroll
    for (int i = 0; i < 4; ++i) {
        const int co = wm * 64 + i * 16 + l4 * 4;
        float sh[4];
#pragma unroll
        for (int e = 0; e < 4; ++e)
            sh[e] = (co + e < Cout) ? bias[co + e] : 0.f;
#pragma unroll
        for (int j = 0; j < 4; ++j) {
            const int ncol = n0 + wn * 64 + j * 16 + l15;
            const int b  = ncol >> logHW;
            const int hw = ncol & (HW - 1);
#pragma unroll
            for (int e = 0; e < 4; ++e) {
                const int c2 = co + e;
                if (c2 < Cout) {
                    const float val = acc[i][j][e] + sh[e];
                    const int a = c2 / DD, cl = c2 - a * DD;
                    out[(size_t)((b + ibase) * TOTAL_ANCH + abase + hw * 9 + a) * 14
                        + coloff + cl] = val;
                }
            }
        }
    }
}

// ---------------------------------------------------------------------------
// R1 128^2 kernel — retained for the 1x1 lateral convs (KS=1, OM=0).
// ---------------------------------------------------------------------------
template <int KS, int OM, bool BNR, int DD>
__global__ __launch_bounds__(256, 3)
void conv_mfma(const ush* __restrict__ Xh, const ush* __restrict__ Xl,
               const ush* __restrict__ Wh, const ush* __restrict__ Wl,
               const float* __restrict__ bias,
               ush* __restrict__ Yh, ush* __restrict__ Yl,
               int K, int logS, int logHW, int Kin)
{
    const int tid = threadIdx.x;

    const int nwg  = gridDim.x * gridDim.y;
    const int flat = blockIdx.y * gridDim.x + blockIdx.x;
    const int xcd = flat & 7, sidx = flat >> 3;
    const int q = nwg >> 3, r8 = nwg & 7;
    const int nf = (xcd < r8 ? xcd * (q + 1) : r8 * (q + 1) + (xcd - r8) * q) + sidx;
    int bx, by;
    if (gridDim.y == 2) { bx = nf >> 1; by = nf & 1; }
    else                { bx = nf;      by = 0;      }

    const int n0  = bx * 128;
    const int co0 = by * 128;
    const int S = 1 << logS, HW = 1 << logHW, P = S + 2;

    __shared__ short lds[4][128][32];

    const int lane = tid & 63;
    const int w = tid >> 6;
    const int wm = w & 1, wn = w >> 1;
    const int l15 = lane & 15, l4 = lane >> 4;

    const int lr = lane >> 2, ls = lane & 3;
    const int sw = ls ^ ((lr >> 1) & 3);
    const ush* gsrc = (w == 0) ? Wh : (w == 1) ? Wl : (w == 2) ? Xh : Xl;
    int sb[8];
    if (w < 2) {
#pragma unroll
        for (int t = 0; t < 8; ++t)
            sb[t] = (co0 + t * 16 + lr) * K + sw * 8;
    } else {
#pragma unroll
        for (int t = 0; t < 8; ++t) {
            const int p = n0 + t * 16 + lr;
            sb[t] = p * Kin + sw * 8;
        }
    }
    short* mypl = &lds[w][0][0];

    const int KC = K >> 5;
    const int slA = (l4 ^ ((l15 >> 1) & 3)) * 8;

    v4f acc[4][4] = {};

    for (int c = 0; c < KC; ++c) {
        const int coff = c * 32;
#pragma unroll
        for (int t = 0; t < 8; ++t)
            gl_lds16(gsrc + (sb[t] + coff), mypl + t * 512);

        __syncthreads();

        v8s ah[4], al[4];
#pragma unroll
        for (int i = 0; i < 4; ++i) {
            ah[i] = *(const v8s*)&lds[0][wm * 64 + i * 16 + l15][slA];
            al[i] = *(const v8s*)&lds[1][wm * 64 + i * 16 + l15][slA];
        }
#pragma unroll
        for (int j = 0; j < 4; ++j) {
            const v8s bh = *(const v8s*)&lds[2][wn * 64 + j * 16 + l15][slA];
            const v8s bl = *(const v8s*)&lds[3][wn * 64 + j * 16 + l15][slA];
#pragma unroll
            for (int i = 0; i < 4; ++i) {
                acc[i][j] = __builtin_amdgcn_mfma_f32_16x16x32_bf16(ah[i], bh, acc[i][j], 0, 0, 0);
                acc[i][j] = __builtin_amdgcn_mfma_f32_16x16x32_bf16(ah[i], bl, acc[i][j], 0, 0, 0);
                acc[i][j] = __builtin_amdgcn_mfma_f32_16x16x32_bf16(al[i], bh, acc[i][j], 0, 0, 0);
            }
        }
        __syncthreads();
    }

#pragma unroll
    for (int i = 0; i < 4; ++i) {
        const int cob = wm * 64 + i * 16 + l4 * 4;
        const int co  = co0 + cob;
        float sh[4];
#pragma unroll
        for (int e = 0; e < 4; ++e) sh[e] = bias[co + e];
#pragma unroll
        for (int j = 0; j < 4; ++j) {
            const int ncol = n0 + wn * 64 + j * 16 + l15;
            const int b  = ncol >> logHW;
            const int hw = ncol & (HW - 1);
            float val[4];
#pragma unroll
            for (int e = 0; e < 4; ++e) val[e] = acc[i][j][e] + sh[e];
            int pidx;
            if (OM == 0) {
                const int oh = hw >> logS, ow = hw & (S - 1);
                pidx = (b * P + oh + 1) * P + ow + 1;
            } else {
                pidx = ncol;
            }
            const int addr = pidx * 256 + co;
            ush hs[4], ls2[4];
#pragma unroll
            for (int e = 0; e < 4; ++e) splitf(val[e], hs[e], ls2[e]);
            *(uint2*)&Yh[addr] = make_uint2(hs[0] | ((unsigned)hs[1] << 16),
                                            hs[2] | ((unsigned)hs[3] << 16));
            *(uint2*)&Yl[addr] = make_uint2(ls2[0] | ((unsigned)ls2[1] << 16),
                                            ls2[2] | ((unsigned)ls2[3] << 16));
        }
    }
}

// ---- prep / glue kernels -------------------------------------------------

__global__ void w3_prep(const float* __restrict__ W, ush* __restrict__ wh,
                        ush* __restrict__ wl, int total) {
    const int idx = blockIdx.x * 256 + threadIdx.x;
    if (idx >= total) return;
    const int co5 = idx / 2304;
    const int kk  = idx - co5 * 2304;
    const int rs = kk >> 8, ci = kk & 255;
    splitf(W[(co5 * 256 + ci) * 9 + rs], wh[idx], wl[idx]);
}

__global__ void w1_prep(const float* __restrict__ W, ush* __restrict__ wh,
                        ush* __restrict__ wl, int Cin, int Kp, int Cout, int total) {
    const int idx = blockIdx.x * 256 + threadIdx.x;
    if (idx >= total) return;
    const int co = idx / Kp;
    const int k  = idx - co * Kp;
    const float x = (co < Cout && k < Cin) ? W[co * Cin + k] : 0.f;
    splitf(x, wh[idx], wl[idx]);
}

__global__ void in_prep(const float* __restrict__ f, ush* __restrict__ xh,
                        ush* __restrict__ xl, int Cin, int Kp, int logHW, int total) {
    const int idx = blockIdx.x * 256 + threadIdx.x;
    if (idx >= total) return;
    const int c = idx % Kp;
    const int n = idx / Kp;
    const int b  = n >> logHW;
    const int hw = n & ((1 << logHW) - 1);
    const float x = (c < Cin) ? f[((b * Cin + c) << logHW) + hw] : 0.f;
    splitf(x, xh[idx], xl[idx]);
}

__global__ void upsample_hl(ush* __restrict__ fh, ush* __restrict__ fl,
                            const ush* __restrict__ ch, const ush* __restrict__ cl2,
                            int logSf, int total) {
    const int idx = blockIdx.x * 256 + threadIdx.x;
    if (idx >= total) return;
    const int ci = idx & 255;
    const int r  = idx >> 8;
    const int Sf = 1 << logSf;
    const int wf = r & (Sf - 1);
    const int hf = (r >> logSf) & (Sf - 1);
    const int b  = r >> (2 * logSf);
    const int Pf = Sf + 2, Pc = (Sf >> 1) + 2;
    const int fi = ((b * Pf + hf + 1) * Pf + wf + 1) * 256 + ci;
    const int cx = ((b * Pc + (hf >> 1) + 1) * Pc + (wf >> 1) + 1) * 256 + ci;
    const float x = bf2f(fh[fi]) + bf2f(fl[fi]) + bf2f(ch[cx]) + bf2f(cl2[cx]);
    splitf(x, fh[fi], fl[fi]);
}

__global__ void ring_zero(ush* __restrict__ yh, ush* __restrict__ yl, int S, int total) {
    const int idx = blockIdx.x * 256 + threadIdx.x;
    if (idx >= total) return;
    const int ci = idx & 255;
    const int r  = idx >> 8;
    const int P = S + 2;
    const int ring = 4 * P - 4;
    const int pr = r % ring;
    const int b  = r / ring;
    int ph, pw;
    if (pr < P)            { ph = 0;     pw = pr; }
    else if (pr < 2 * P)   { ph = P - 1; pw = pr - P; }
    else { const int q = pr - 2 * P; ph = 1 + (q >> 1); pw = (q & 1) ? (P - 1) : 0; }
    const int a = ((b * P + ph) * P + pw) * 256 + ci;
    yh[a] = 0; yl[a] = 0;
}

// ---------------------------------------------------------------------------

extern "C" void kernel_launch(void* const* d_in, const int* in_sizes, int n_in,
                              void* d_out, int out_size, void* d_ws, size_t ws_size,
                              hipStream_t stream)
{
    const float* f[5];     const float* lat_w[5];
    for (int i = 0; i < 5; ++i) f[i] = (const float*)d_in[i];
    for (int i = 0; i < 5; ++i) lat_w[i] = (const float*)d_in[5 + i];
    const float* lat_b  = (const float*)d_in[10];
    const float* fpn_w  = (const float*)d_in[11];
    const float* fpn_b  = (const float*)d_in[12];
    const float* cls_w1 = (const float*)d_in[13];
    const float* cls_b1 = (const float*)d_in[14];
    const float* cls_g  = (const float*)d_in[15];
    const float* cls_bt = (const float*)d_in[16];
    const float* cls_m  = (const float*)d_in[17];
    const float* cls_v  = (const float*)d_in[18];
    const float* cls_w2 = (const float*)d_in[19];
    const float* cls_b2 = (const float*)d_in[20];
    const float* reg_w1 = (const float*)d_in[21];
    const float* reg_b1 = (const float*)d_in[22];
    const float* reg_g  = (const float*)d_in[23];
    const float* reg_bt = (const float*)d_in[24];
    const float* reg_m  = (const float*)d_in[25];
    const float* reg_v  = (const float*)d_in[26];
    const float* reg_w2 = (const float*)d_in[27];
    const float* reg_b2 = (const float*)d_in[28];

    float* out = (float*)d_out;
    ush*   ws16 = (ush*)d_ws;

    static const int S_[5]     = {128, 64, 32, 16, 8};
    static const int logS_[5]  = {7, 6, 5, 4, 3};
    static const int logHW_[5] = {14, 12, 10, 8, 6};
    static const int HW_[5]    = {16384, 4096, 1024, 256, 64};
    static const int Cin_[5]   = {32, 48, 96, 136, 232};
    static const int Kp_[5]    = {32, 64, 96, 160, 256};
    static const int abase_[5] = {0, 147456, 184320, 193536, 195840};
    constexpr int BIG = 0x7fffffff;

    size_t off = 0;
    auto alloc = [&](size_t elems) {
        ush* p = ws16 + off;
        off += (elems + 63) & ~(size_t)63;
        return p;
    };

    // --- persistent: padded lateral planes (reused as head-conv1 tmp) ---
    ush *lat_h[5], *lat_l[5];
    for (int i = 0; i < 5; ++i) {
        const int P = S_[i] + 2;
        const size_t e = (size_t)2048 * P * P;   // 8 images * P*P * 256
        lat_h[i] = alloc(e); lat_l[i] = alloc(e);
    }
    const size_t lat_bytes = off * sizeof(ush);

    // --- shared transient arena (69.2 MB) ---
    const size_t ARENA_E = (size_t)2 * 4 * 130 * 130 * 256;
    ush* arena = alloc(ARENA_E);

    // --- weights (head conv2 padded to 128 co-rows for unguarded DMA) ---
    ush* fw_h = alloc((size_t)5 * 256 * 2304); ush* fw_l = alloc((size_t)5 * 256 * 2304);
    ush* cw_h = alloc(256 * 2304);             ush* cw_l = alloc(256 * 2304);
    ush* rw_h = alloc(256 * 2304);             ush* rw_l = alloc(256 * 2304);
    ush *lw_h[5], *lw_l[5];
    for (int i = 0; i < 5; ++i) { lw_h[i] = alloc(256 * Kp_[i]); lw_l[i] = alloc(256 * Kp_[i]); }
    ush* c2_h = alloc(128 * 256); ush* c2_l = alloc(128 * 256);
    ush* r2_h = alloc(128 * 256); ush* r2_l = alloc(128 * 256);

    hipMemsetAsync(ws16, 0, lat_bytes, stream);

    // --- weight prep ---
    {
        int t = 5 * 256 * 2304;
        w3_prep<<<dim3((t + 255) / 256), 256, 0, stream>>>(fpn_w, fw_h, fw_l, t);
        t = 256 * 2304;
        w3_prep<<<dim3((t + 255) / 256), 256, 0, stream>>>(cls_w1, cw_h, cw_l, t);
        w3_prep<<<dim3((t + 255) / 256), 256, 0, stream>>>(reg_w1, rw_h, rw_l, t);
        for (int i = 0; i < 5; ++i) {
            t = 256 * Kp_[i];
            w1_prep<<<dim3((t + 255) / 256), 256, 0, stream>>>(lat_w[i], lw_h[i], lw_l[i], Cin_[i], Kp_[i], 256, t);
        }
        t = 128 * 256;
        w1_prep<<<dim3((t + 255) / 256), 256, 0, stream>>>(cls_w2, c2_h, c2_l, 256, 256, 90, t);
        w1_prep<<<dim3((t + 255) / 256), 256, 0, stream>>>(reg_w2, r2_h, r2_l, 256, 256, 36, t);
    }

    // --- input conversion + lateral 1x1 convs (arena transient) ---
    for (int i = 0; i < 5; ++i) {
        const int N = 8 * HW_[i];
        const int t = N * Kp_[i];
        ush* xh = arena;
        ush* xl = arena + (size_t)N * Kp_[i];
        in_prep<<<dim3((t + 255) / 256), 256, 0, stream>>>(f[i], xh, xl, Cin_[i], Kp_[i], logHW_[i], t);
        conv_mfma<1, 0, false, 0><<<dim3(N / 128, 2), 256, 0, stream>>>(
            xh, xl, lw_h[i], lw_l[i], lat_b + i * 256,
            lat_h[i], lat_l[i],
            Kp_[i], logS_[i], logHW_[i], Kp_[i]);
    }

    // --- top-down pathway ---
    for (int i = 4; i >= 1; --i) {
        const int t = 8 * HW_[i - 1] * 256;
        upsample_hl<<<dim3((t + 255) / 256), 256, 0, stream>>>(
            lat_h[i - 1], lat_l[i - 1], lat_h[i], lat_l[i], logS_[i - 1], t);
    }

    // --- levels 1..4 FUSED: all 4 fpn plane pairs resident in arena ---
    ush *fpn_h4[5], *fpn_l4[5];
    {
        size_t o = 0;
        for (int i = 1; i < 5; ++i) {
            const int P = S_[i] + 2;
            fpn_h4[i] = arena + o; o += (size_t)2048 * P * P;
            fpn_l4[i] = arena + o; o += (size_t)2048 * P * P;
        }
    }
    for (int i = 1; i < 5; ++i) {
        const int P = S_[i] + 2;
        const int rt = 8 * (4 * P - 4) * 256;
        ring_zero<<<dim3((rt + 255) / 256), 256, 0, stream>>>(fpn_h4[i], fpn_l4[i], S_[i], rt);
    }
    static const int bstart4[4] = {0, 128, 160, 168};   // 128+32+8+2 = 170 (256px blocks)
    static const int bstartS[4] = {0, 256, 320, 336};   // 340 (128px blocks, conv_sf)

    {   // fused fpn conv (per-level weight slice + bias)
        Tab3 T{};
        for (int k = 0; k < 4; ++k) {
            const int i = k + 1;
            T.l[k] = Lvl3{ lat_h[i], lat_l[i], fpn_h4[i], fpn_l4[i],
                           fpn_b + i * 256, i * 256 * 2304,
                           logS_[i], logHW_[i], bstart4[k] };
        }
        conv3g<0, false><<<dim3(170), 512, 0, stream>>>(
            T, fw_h, fw_l, nullptr, nullptr, nullptr, nullptr);
    }
    {   // fused cls conv1 -> tmp (lat planes)
        Tab3 T{};
        for (int k = 0; k < 4; ++k) {
            const int i = k + 1;
            T.l[k] = Lvl3{ fpn_h4[i], fpn_l4[i], lat_h[i], lat_l[i],
                           cls_b1, 0, logS_[i], logHW_[i], bstart4[k] };
        }
        conv3g<1, true><<<dim3(170), 512, 0, stream>>>(
            T, cw_h, cw_l, cls_g, cls_bt, cls_m, cls_v);
    }
    {   // fused cls conv2 scatter
        TabS T{};
        for (int k = 0; k < 4; ++k) {
            const int i = k + 1;
            T.l[k] = LvlS{ lat_h[i], lat_l[i], abase_[i], logHW_[i], bstartS[k], 0 };
        }
        conv_sf<10><<<dim3(340), 256, 0, stream>>>(T, c2_h, c2_l, cls_b2, out);
    }
    {   // fused reg conv1 -> tmp
        Tab3 T{};
        for (int k = 0; k < 4; ++k) {
            const int i = k + 1;
            T.l[k] = Lvl3{ fpn_h4[i], fpn_l4[i], lat_h[i], lat_l[i],
                           reg_b1, 0, logS_[i], logHW_[i], bstart4[k] };
        }
        conv3g<1, true><<<dim3(170), 512, 0, stream>>>(
            T, rw_h, rw_l, reg_g, reg_bt, reg_m, reg_v);
    }
    {   // fused reg conv2 scatter
        TabS T{};
        for (int k = 0; k < 4; ++k) {
            const int i = k + 1;
            T.l[k] = LvlS{ lat_h[i], lat_l[i], abase_[i], logHW_[i], bstartS[k], 0 };
        }
        conv_sf<4><<<dim3(340), 256, 0, stream>>>(T, r2_h, r2_l, reg_b2, out);
    }

    // --- level 0: two 4-image groups (1-entry tables; 256 blocks = 1 round) ---
    {
        const int P = 130;
        const size_t padg = (size_t)4 * P * P * 256;     // padded, 4 images
        const size_t unpg = (size_t)4 * 16384 * 256;     // unpadded, 4 images
        for (int g = 0; g < 2; ++g) {
            ush* fpn_h = arena;
            ush* fpn_l = arena + padg;
            ush* lat0p_h = lat_h[0] + (size_t)g * padg;
            ush* lat0p_l = lat_l[0] + (size_t)g * padg;
            ush* tmp_h   = lat_h[0] + (size_t)g * unpg;
            ush* tmp_l   = lat_l[0] + (size_t)g * unpg;
            const int rt = 4 * (4 * P - 4) * 256;
            ring_zero<<<dim3((rt + 255) / 256), 256, 0, stream>>>(fpn_h, fpn_l, 128, rt);

            Tab3 T{};
            T.l[0] = Lvl3{ lat0p_h, lat0p_l, fpn_h, fpn_l, fpn_b, 0, 7, 14, 0 };
            for (int k = 1; k < 4; ++k) T.l[k].bstart = BIG;
            conv3g<0, false><<<dim3(256), 512, 0, stream>>>(
                T, fw_h, fw_l, nullptr, nullptr, nullptr, nullptr);

            Tab3 Tc{};
            Tc.l[0] = Lvl3{ fpn_h, fpn_l, tmp_h, tmp_l, cls_b1, 0, 7, 14, 0 };
            for (int k = 1; k < 4; ++k) Tc.l[k].bstart = BIG;
            conv3g<1, true><<<dim3(256), 512, 0, stream>>>(
                Tc, cw_h, cw_l, cls_g, cls_bt, cls_m, cls_v);

            TabS Ts{};
            Ts.l[0] = LvlS{ tmp_h, tmp_l, 0, 14, 0, 4 * g };
            for (int k = 1; k < 4; ++k) Ts.l[k].bstart = BIG;
            conv_sf<10><<<dim3(512), 256, 0, stream>>>(Ts, c2_h, c2_l, cls_b2, out);

            Tab3 Tr{};
            Tr.l[0] = Lvl3{ fpn_h, fpn_l, tmp_h, tmp_l, reg_b1, 0, 7, 14, 0 };
            for (int k = 1; k < 4; ++k) Tr.l[k].bstart = BIG;
            conv3g<1, true><<<dim3(256), 512, 0, stream>>>(
                Tr, rw_h, rw_l, reg_g, reg_bt, reg_m, reg_v);

            TabS Tq{};
            Tq.l[0] = LvlS{ tmp_h, tmp_l, 0, 14, 0, 4 * g };
            for (int k = 1; k < 4; ++k) Tq.l[k].bstart = BIG;
            conv_sf<4><<<dim3(512), 256, 0, stream>>>(Tq, r2_h, r2_l, reg_b2, out);
        }
    }
}